// Round 1
// baseline (394.964 us; speedup 1.0000x reference)
//
#include <hip/hip_runtime.h>

#define C_   512
#define HW_  4096
#define NTOK 8192

typedef __attribute__((ext_vector_type(8))) short bf16x8;
typedef __attribute__((ext_vector_type(4))) float f32x4;
typedef unsigned short u16;

#define MFMA16 __builtin_amdgcn_mfma_f32_16x16x32_bf16

__device__ __forceinline__ u16 f2bf(float f) {
  unsigned int u = __float_as_uint(f);
  u += 0x7fffu + ((u >> 16) & 1u);
  return (u16)(u >> 16);
}

// ---------------- weight fp32 -> bf16 cast (4 matrices of 512x512) ----------
__global__ void wcast_kernel(const float* __restrict__ a, const float* __restrict__ b,
                             const float* __restrict__ c, const float* __restrict__ d,
                             u16* __restrict__ out) {
  int gid = blockIdx.x * 256 + threadIdx.x;   // 262144 threads, 4 floats each
  int which = gid >> 16;
  const float* src = which == 0 ? a : which == 1 ? b : which == 2 ? c : d;
  int loc = (gid & 65535) * 4;
  float4 v = *(const float4*)(src + loc);
  ushort4 o;
  o.x = f2bf(v.x); o.y = f2bf(v.y); o.z = f2bf(v.z); o.w = f2bf(v.w);
  *(ushort4*)(out + ((size_t)which << 18) + loc) = o;
}

// ---------------- GroupNorm stats: one block per (batch, group) -------------
__global__ __launch_bounds__(256) void gn_stats_kernel(const float* __restrict__ x,
                                                       float* __restrict__ gstat) {
  const int blk = blockIdx.x;  // b*32+g, slice is contiguous 65536 floats
  const float4* p = (const float4*)(x + (size_t)blk * 65536);
  float s = 0.0f, ss = 0.0f;
  for (int i = threadIdx.x; i < 16384; i += 256) {
    float4 v = p[i];
    s  += v.x + v.y + v.z + v.w;
    ss += v.x * v.x + v.y * v.y + v.z * v.z + v.w * v.w;
  }
  #pragma unroll
  for (int m = 1; m < 64; m <<= 1) { s += __shfl_xor(s, m); ss += __shfl_xor(ss, m); }
  __shared__ float rs[4], rss[4];
  const int wv = threadIdx.x >> 6;
  if ((threadIdx.x & 63) == 0) { rs[wv] = s; rss[wv] = ss; }
  __syncthreads();
  if (threadIdx.x == 0) {
    float S  = rs[0] + rs[1] + rs[2] + rs[3];
    float SS = rss[0] + rss[1] + rss[2] + rss[3];
    float mean = S * (1.0f / 65536.0f);
    float var  = fmaxf(SS * (1.0f / 65536.0f) - mean * mean, 0.0f);
    gstat[2 * blk]     = mean;
    gstat[2 * blk + 1] = rsqrtf(var + 1e-6f);
  }
}

// ---------------- GN apply + transpose to token-major bf16 hT[8192][512] ----
__global__ __launch_bounds__(256) void gn_apply_kernel(const float* __restrict__ x,
                                                       const float* __restrict__ gnw,
                                                       const float* __restrict__ gnb,
                                                       const float* __restrict__ gstat,
                                                       u16* __restrict__ hT) {
  const int b = blockIdx.z, c0 = blockIdx.y * 64, hw0 = blockIdx.x * 64;
  const int t = threadIdx.x;
  __shared__ float tile[64][65];
  {
    const int tx = t & 63, ty = t >> 6;  // ty 0..3
    #pragma unroll
    for (int i = 0; i < 16; ++i) {
      int cl = ty * 16 + i;
      int c = c0 + cl;
      int g = b * 32 + (c >> 4);
      float mean = gstat[2 * g], rstd = gstat[2 * g + 1];
      float val = x[((size_t)(b * C_ + c)) * HW_ + hw0 + tx];
      tile[cl][tx] = (val - mean) * rstd * gnw[c] + gnb[c];
    }
  }
  __syncthreads();
  {
    const int cx = (t & 31) * 2, ty = t >> 5;  // ty 0..7
    #pragma unroll
    for (int i = 0; i < 8; ++i) {
      int hwl = ty * 8 + i;
      unsigned pk = (unsigned)f2bf(tile[cx][hwl]) | ((unsigned)f2bf(tile[cx + 1][hwl]) << 16);
      *(unsigned*)&hT[((size_t)(b * HW_ + hw0 + hwl)) * C_ + c0 + cx] = pk;
    }
  }
}

// ---------------- generic bf16 A(MxK) @ B(NxK)^T GEMM, 64x64 tile -----------
// BIAS_N: bias indexed by n (else by m). RESID: fp32 out + residual add.
template<int BIAS_N, int RESID>
__global__ __launch_bounds__(256, 4) void gemm_abt(
    const u16* __restrict__ A, int lda,
    const u16* __restrict__ B, int ldb, long bz,
    const float* __restrict__ bias,
    const float* __restrict__ resid,
    void* __restrict__ Dp, int ldd, long dz, int K)
{
  B += (size_t)blockIdx.z * (size_t)bz;
  const int t = threadIdx.x;
  const int m0 = blockIdx.x * 64, n0 = blockIdx.y * 64;
  const int wv = t >> 6, l = t & 63, lr = l & 15, lq = l >> 4;
  const int ro = (wv >> 1) * 32, co = (wv & 1) * 32;
  __shared__ u16 As[64][72];
  __shared__ u16 Bs[64][72];
  f32x4 acc[2][2] = {};
  const int ldr_ = t >> 2;
  const int ldc_ = (t & 3) * 16;
  for (int k0 = 0; k0 < K; k0 += 64) {
    *(uint4*)&As[ldr_][ldc_]     = *(const uint4*)(A + (size_t)(m0 + ldr_) * lda + k0 + ldc_);
    *(uint4*)&As[ldr_][ldc_ + 8] = *(const uint4*)(A + (size_t)(m0 + ldr_) * lda + k0 + ldc_ + 8);
    *(uint4*)&Bs[ldr_][ldc_]     = *(const uint4*)(B + (size_t)(n0 + ldr_) * ldb + k0 + ldc_);
    *(uint4*)&Bs[ldr_][ldc_ + 8] = *(const uint4*)(B + (size_t)(n0 + ldr_) * ldb + k0 + ldc_ + 8);
    __syncthreads();
    #pragma unroll
    for (int kk = 0; kk < 64; kk += 32) {
      bf16x8 a0 = *(const bf16x8*)&As[ro + lr][kk + lq * 8];
      bf16x8 a1 = *(const bf16x8*)&As[ro + 16 + lr][kk + lq * 8];
      bf16x8 b0 = *(const bf16x8*)&Bs[co + lr][kk + lq * 8];
      bf16x8 b1 = *(const bf16x8*)&Bs[co + 16 + lr][kk + lq * 8];
      acc[0][0] = MFMA16(a0, b0, acc[0][0], 0, 0, 0);
      acc[0][1] = MFMA16(a0, b1, acc[0][1], 0, 0, 0);
      acc[1][0] = MFMA16(a1, b0, acc[1][0], 0, 0, 0);
      acc[1][1] = MFMA16(a1, b1, acc[1][1], 0, 0, 0);
    }
    __syncthreads();
  }
  #pragma unroll
  for (int rf = 0; rf < 2; ++rf) {
    #pragma unroll
    for (int cf = 0; cf < 2; ++cf) {
      const int n = n0 + co + cf * 16 + lr;
      const float bn = BIAS_N ? bias[n] : 0.0f;
      #pragma unroll
      for (int reg = 0; reg < 4; ++reg) {
        const int m = m0 + ro + rf * 16 + lq * 4 + reg;
        float val = acc[rf][cf][reg] + (BIAS_N ? bn : bias[m]);
        if (RESID) {
          float* D = (float*)Dp + (size_t)blockIdx.z * dz;
          const float* R = resid + (size_t)blockIdx.z * dz;
          size_t idx = (size_t)m * ldd + n;
          D[idx] = val + R[idx];
        } else {
          ((u16*)Dp)[(size_t)m * ldd + n] = f2bf(val);
        }
      }
    }
  }
}

// ---------------- fused attention (no-max softmax, j-split partials) --------
// grid (64 i-blocks of 64 rows, 2 j-chunks of 2048, 2 batches), 512 threads.
// q,k token-major [8192][512]; v channel-major [512][8192].
__global__ __launch_bounds__(512, 2) void attn_kernel(
    const u16* __restrict__ q, const u16* __restrict__ k,
    const u16* __restrict__ v, float* __restrict__ Opart,
    float* __restrict__ rspart)
{
  const int t = threadIdx.x;
  const int wv = t >> 6, l = t & 63, lr = l & 15, lq = l >> 4;
  const int rh = wv >> 2, jq = wv & 3;
  const int i0 = blockIdx.x * 64, jc = blockIdx.y, b = blockIdx.z;

  __shared__ u16 Ps[64][264];        // +8 pad: 2-way banks on b128 reads (free)
  __shared__ float rsred[8][64];

  f32x4 oacc[2][8] = {};             // per-wave O: rows rh*32+32, cols jq*128+128
  float rs_acc[2][4] = {};
  const float SCL2 = 0.06376774487989831f;  // log2(e)/sqrt(512)

  const size_t qrow = (size_t)(b * HW_ + i0 + rh * 32 + lr) * C_ + lq * 8;

  for (int jt = 0; jt < 8; ++jt) {
    const int j0 = jc * 2048 + jt * 256;
    const size_t krow = (size_t)(b * HW_ + j0 + jq * 64 + lr) * C_ + lq * 8;
    // ---- scores: per-wave 32x64 tile over K=512 ----
    f32x4 s[2][4] = {};
    #pragma unroll 4
    for (int k0 = 0; k0 < 512; k0 += 32) {
      bf16x8 aq[2], bk[4];
      #pragma unroll
      for (int rf = 0; rf < 2; ++rf)
        aq[rf] = *(const bf16x8*)(q + qrow + (size_t)rf * (16 * C_) + k0);
      #pragma unroll
      for (int cf = 0; cf < 4; ++cf)
        bk[cf] = *(const bf16x8*)(k + krow + (size_t)cf * (16 * C_) + k0);
      #pragma unroll
      for (int rf = 0; rf < 2; ++rf)
        #pragma unroll
        for (int cf = 0; cf < 4; ++cf)
          s[rf][cf] = MFMA16(aq[rf], bk[cf], s[rf][cf], 0, 0, 0);
    }
    // ---- exp, rowsum partial (shfl butterfly over lr), Ps write ----
    #pragma unroll
    for (int rf = 0; rf < 2; ++rf) {
      #pragma unroll
      for (int reg = 0; reg < 4; ++reg) {
        float rsum = 0.0f;
        #pragma unroll
        for (int cf = 0; cf < 4; ++cf) {
          float p = exp2f(s[rf][cf][reg] * SCL2);
          s[rf][cf][reg] = p;
          rsum += p;
        }
        rsum += __shfl_xor(rsum, 1);
        rsum += __shfl_xor(rsum, 2);
        rsum += __shfl_xor(rsum, 4);
        rsum += __shfl_xor(rsum, 8);
        rs_acc[rf][reg] += rsum;
        const int prow = rh * 32 + rf * 16 + lq * 4 + reg;
        #pragma unroll
        for (int cf = 0; cf < 4; ++cf)
          Ps[prow][jq * 64 + cf * 16 + lr] = f2bf(s[rf][cf][reg]);
      }
    }
    __syncthreads();
    // ---- PV: per-wave 32 rows x 128 cols, K = 256 (this j-tile) ----
    const size_t vrow = (size_t)(jq * 128 + lr) * NTOK + b * HW_ + j0 + lq * 8;
    for (int js = 0; js < 8; ++js) {
      bf16x8 ap[2], vb[8];
      #pragma unroll
      for (int rf = 0; rf < 2; ++rf)
        ap[rf] = *(const bf16x8*)&Ps[rh * 32 + rf * 16 + lr][js * 32 + lq * 8];
      #pragma unroll
      for (int cf = 0; cf < 8; ++cf)
        vb[cf] = *(const bf16x8*)(v + vrow + (size_t)cf * (16 * NTOK) + js * 32);
      #pragma unroll
      for (int rf = 0; rf < 2; ++rf)
        #pragma unroll
        for (int cf = 0; cf < 8; ++cf)
          oacc[rf][cf] = MFMA16(ap[rf], vb[cf], oacc[rf][cf], 0, 0, 0);
    }
    __syncthreads();
  }
  // ---- rowsum partials: cross-wave reduce, one value per row ----
  if (lr == 0) {
    #pragma unroll
    for (int rf = 0; rf < 2; ++rf)
      #pragma unroll
      for (int reg = 0; reg < 4; ++reg)
        rsred[wv][rh * 32 + rf * 16 + lq * 4 + reg] = rs_acc[rf][reg];
  }
  __syncthreads();
  if (wv == 0) {
    const int row = l;
    const int base = (row >> 5) * 4;
    float tot = rsred[base][row] + rsred[base + 1][row] + rsred[base + 2][row] + rsred[base + 3][row];
    rspart[(size_t)jc * NTOK + b * HW_ + i0 + row] = tot;
  }
  // ---- unnormalized O partial (fp32, token-major) ----
  #pragma unroll
  for (int rf = 0; rf < 2; ++rf) {
    #pragma unroll
    for (int reg = 0; reg < 4; ++reg) {
      const size_t orow = ((size_t)jc * NTOK + b * HW_ + i0 + rh * 32 + rf * 16 + lq * 4 + reg) * C_ + jq * 128;
      #pragma unroll
      for (int cf = 0; cf < 8; ++cf)
        Opart[orow + cf * 16 + lr] = oacc[rf][cf][reg];
    }
  }
}

// ---------------- combine the 2 j-chunk partials, normalize, -> bf16 --------
__global__ __launch_bounds__(256) void combine_kernel(const float* __restrict__ Opart,
                                                      const float* __restrict__ rspart,
                                                      u16* __restrict__ ao) {
  const size_t idx4 = ((size_t)blockIdx.x * 256 + threadIdx.x) * 4;  // < 8192*512
  const int tok = (int)(idx4 >> 9);
  const float inv = 1.0f / (rspart[tok] + rspart[NTOK + tok]);
  f32x4 a  = *(const f32x4*)(Opart + idx4);
  f32x4 b2 = *(const f32x4*)(Opart + (size_t)NTOK * C_ + idx4);
  ushort4 o;
  o.x = f2bf((a.x + b2.x) * inv);
  o.y = f2bf((a.y + b2.y) * inv);
  o.z = f2bf((a.z + b2.z) * inv);
  o.w = f2bf((a.w + b2.w) * inv);
  *(ushort4*)(ao + idx4) = o;
}

extern "C" void kernel_launch(void* const* d_in, const int* in_sizes, int n_in,
                              void* d_out, int out_size, void* d_ws, size_t ws_size,
                              hipStream_t stream) {
  const float* x   = (const float*)d_in[0];
  const float* gnw = (const float*)d_in[1];
  const float* gnb = (const float*)d_in[2];
  const float* qw  = (const float*)d_in[3];
  const float* qb  = (const float*)d_in[4];
  const float* kw  = (const float*)d_in[5];
  const float* kb  = (const float*)d_in[6];
  const float* vw  = (const float*)d_in[7];
  const float* vb  = (const float*)d_in[8];
  const float* pw  = (const float*)d_in[9];
  const float* pb  = (const float*)d_in[10];

  // workspace layout (77,660,672 bytes total, all 256B-aligned)
  char* ws = (char*)d_ws;
  u16*   wqb   = (u16*)(ws + 0);             //  512*512 bf16 x4
  u16*   wkb   = wqb + 262144;
  u16*   wvb   = wkb + 262144;
  u16*   wpb   = wvb + 262144;
  float* gstat = (float*)(ws + 2097152);     //  64 x (mean, rstd)
  u16*   hT    = (u16*)(ws + 2097664);       //  [8192][512] bf16
  u16*   qm    = (u16*)(ws + 10486272);      //  [8192][512] bf16
  u16*   km    = (u16*)(ws + 18874880);      //  [8192][512] bf16
  u16*   vm    = (u16*)(ws + 27263488);      //  [512][8192] bf16
  u16*   ao    = (u16*)(ws + 35652096);      //  [8192][512] bf16
  float* Opart = (float*)(ws + 44040704);    //  [2][8192][512] f32
  float* rsp   = (float*)(ws + 77595136);    //  [2][8192] f32

  wcast_kernel<<<1024, 256, 0, stream>>>(qw, kw, vw, pw, wqb);
  gn_stats_kernel<<<64, 256, 0, stream>>>(x, gstat);
  gn_apply_kernel<<<dim3(64, 8, 2), 256, 0, stream>>>(x, gnw, gnb, gstat, hT);
  // q, k: token-major, bias per-n
  gemm_abt<1, 0><<<dim3(128, 8), 256, 0, stream>>>(hT, 512, wqb, 512, 0, qb, nullptr, qm, 512, 0, 512);
  gemm_abt<1, 0><<<dim3(128, 8), 256, 0, stream>>>(hT, 512, wkb, 512, 0, kb, nullptr, km, 512, 0, 512);
  // v: channel-major, bias per-m
  gemm_abt<0, 0><<<dim3(8, 128), 256, 0, stream>>>(wvb, 512, hT, 512, 0, vb, nullptr, vm, 8192, 0, 512);
  attn_kernel<<<dim3(64, 2, 2), 512, 0, stream>>>(qm, km, vm, Opart, rsp);
  combine_kernel<<<4096, 256, 0, stream>>>(Opart, rsp, ao);
  // proj + bias + residual, fp32 out, per-batch via blockIdx.z
  gemm_abt<0, 1><<<dim3(8, 64, 2), 256, 0, stream>>>(wpb, 512, ao, 512, 2097152L, pb, x, d_out, 4096, 2097152L, 512);
}

// Round 2
// 376.970 us; speedup vs baseline: 1.0477x; 1.0477x over previous
//
#include <hip/hip_runtime.h>

#define C_   512
#define HW_  4096
#define NTOK 8192

typedef __attribute__((ext_vector_type(8))) short bf16x8;
typedef __attribute__((ext_vector_type(4))) float f32x4;
typedef unsigned short u16;

#define MFMA16 __builtin_amdgcn_mfma_f32_16x16x32_bf16

__device__ __forceinline__ u16 f2bf(float f) {
  unsigned int u = __float_as_uint(f);
  u += 0x7fffu + ((u >> 16) & 1u);
  return (u16)(u >> 16);
}

// ---------------- weight fp32 -> bf16 cast (4 matrices of 512x512) ----------
__global__ void wcast_kernel(const float* __restrict__ a, const float* __restrict__ b,
                             const float* __restrict__ c, const float* __restrict__ d,
                             u16* __restrict__ out) {
  int gid = blockIdx.x * 256 + threadIdx.x;   // 262144 threads, 4 floats each
  int which = gid >> 16;
  const float* src = which == 0 ? a : which == 1 ? b : which == 2 ? c : d;
  int loc = (gid & 65535) * 4;
  float4 v = *(const float4*)(src + loc);
  ushort4 o;
  o.x = f2bf(v.x); o.y = f2bf(v.y); o.z = f2bf(v.z); o.w = f2bf(v.w);
  *(ushort4*)(out + ((size_t)which << 18) + loc) = o;
}

// ---------------- GroupNorm stats: one block per (batch, group) -------------
__global__ __launch_bounds__(256) void gn_stats_kernel(const float* __restrict__ x,
                                                       float* __restrict__ gstat) {
  const int blk = blockIdx.x;  // b*32+g, slice is contiguous 65536 floats
  const float4* p = (const float4*)(x + (size_t)blk * 65536);
  float s = 0.0f, ss = 0.0f;
  for (int i = threadIdx.x; i < 16384; i += 256) {
    float4 v = p[i];
    s  += v.x + v.y + v.z + v.w;
    ss += v.x * v.x + v.y * v.y + v.z * v.z + v.w * v.w;
  }
  #pragma unroll
  for (int m = 1; m < 64; m <<= 1) { s += __shfl_xor(s, m); ss += __shfl_xor(ss, m); }
  __shared__ float rs[4], rss[4];
  const int wv = threadIdx.x >> 6;
  if ((threadIdx.x & 63) == 0) { rs[wv] = s; rss[wv] = ss; }
  __syncthreads();
  if (threadIdx.x == 0) {
    float S  = rs[0] + rs[1] + rs[2] + rs[3];
    float SS = rss[0] + rss[1] + rss[2] + rss[3];
    float mean = S * (1.0f / 65536.0f);
    float var  = fmaxf(SS * (1.0f / 65536.0f) - mean * mean, 0.0f);
    gstat[2 * blk]     = mean;
    gstat[2 * blk + 1] = rsqrtf(var + 1e-6f);
  }
}

// ---------------- GN apply + transpose to token-major bf16 hT[8192][512] ----
__global__ __launch_bounds__(256) void gn_apply_kernel(const float* __restrict__ x,
                                                       const float* __restrict__ gnw,
                                                       const float* __restrict__ gnb,
                                                       const float* __restrict__ gstat,
                                                       u16* __restrict__ hT) {
  const int b = blockIdx.z, c0 = blockIdx.y * 64, hw0 = blockIdx.x * 64;
  const int t = threadIdx.x;
  __shared__ float tile[64][65];
  {
    const int tx = t & 63, ty = t >> 6;  // ty 0..3
    #pragma unroll
    for (int i = 0; i < 16; ++i) {
      int cl = ty * 16 + i;
      int c = c0 + cl;
      int g = b * 32 + (c >> 4);
      float mean = gstat[2 * g], rstd = gstat[2 * g + 1];
      float val = x[((size_t)(b * C_ + c)) * HW_ + hw0 + tx];
      tile[cl][tx] = (val - mean) * rstd * gnw[c] + gnb[c];
    }
  }
  __syncthreads();
  {
    const int cx = (t & 31) * 2, ty = t >> 5;  // ty 0..7
    #pragma unroll
    for (int i = 0; i < 8; ++i) {
      int hwl = ty * 8 + i;
      unsigned pk = (unsigned)f2bf(tile[cx][hwl]) | ((unsigned)f2bf(tile[cx + 1][hwl]) << 16);
      *(unsigned*)&hT[((size_t)(b * HW_ + hw0 + hwl)) * C_ + c0 + cx] = pk;
    }
  }
}

// ---------------- generic bf16 A(MxK) @ B(NxK)^T GEMM, 64x64 tile -----------
// BIAS_N: bias indexed by n (else by m). RESID: fp32 out + residual add.
template<int BIAS_N, int RESID>
__global__ __launch_bounds__(256, 4) void gemm_abt(
    const u16* __restrict__ A, int lda,
    const u16* __restrict__ B, int ldb, long bz,
    const float* __restrict__ bias,
    const float* __restrict__ resid,
    void* __restrict__ Dp, int ldd, long dz, int K)
{
  B += (size_t)blockIdx.z * (size_t)bz;
  const int t = threadIdx.x;
  const int m0 = blockIdx.x * 64, n0 = blockIdx.y * 64;
  const int wv = t >> 6, l = t & 63, lr = l & 15, lq = l >> 4;
  const int ro = (wv >> 1) * 32, co = (wv & 1) * 32;
  __shared__ u16 As[64][72];
  __shared__ u16 Bs[64][72];
  f32x4 acc[2][2] = {};
  const int ldr_ = t >> 2;
  const int ldc_ = (t & 3) * 16;
  for (int k0 = 0; k0 < K; k0 += 64) {
    *(uint4*)&As[ldr_][ldc_]     = *(const uint4*)(A + (size_t)(m0 + ldr_) * lda + k0 + ldc_);
    *(uint4*)&As[ldr_][ldc_ + 8] = *(const uint4*)(A + (size_t)(m0 + ldr_) * lda + k0 + ldc_ + 8);
    *(uint4*)&Bs[ldr_][ldc_]     = *(const uint4*)(B + (size_t)(n0 + ldr_) * ldb + k0 + ldc_);
    *(uint4*)&Bs[ldr_][ldc_ + 8] = *(const uint4*)(B + (size_t)(n0 + ldr_) * ldb + k0 + ldc_ + 8);
    __syncthreads();
    #pragma unroll
    for (int kk = 0; kk < 64; kk += 32) {
      bf16x8 a0 = *(const bf16x8*)&As[ro + lr][kk + lq * 8];
      bf16x8 a1 = *(const bf16x8*)&As[ro + 16 + lr][kk + lq * 8];
      bf16x8 b0 = *(const bf16x8*)&Bs[co + lr][kk + lq * 8];
      bf16x8 b1 = *(const bf16x8*)&Bs[co + 16 + lr][kk + lq * 8];
      acc[0][0] = MFMA16(a0, b0, acc[0][0], 0, 0, 0);
      acc[0][1] = MFMA16(a0, b1, acc[0][1], 0, 0, 0);
      acc[1][0] = MFMA16(a1, b0, acc[1][0], 0, 0, 0);
      acc[1][1] = MFMA16(a1, b1, acc[1][1], 0, 0, 0);
    }
    __syncthreads();
  }
  #pragma unroll
  for (int rf = 0; rf < 2; ++rf) {
    #pragma unroll
    for (int cf = 0; cf < 2; ++cf) {
      const int n = n0 + co + cf * 16 + lr;
      const float bn = BIAS_N ? bias[n] : 0.0f;
      #pragma unroll
      for (int reg = 0; reg < 4; ++reg) {
        const int m = m0 + ro + rf * 16 + lq * 4 + reg;
        float val = acc[rf][cf][reg] + (BIAS_N ? bn : bias[m]);
        if (RESID) {
          float* D = (float*)Dp + (size_t)blockIdx.z * dz;
          const float* R = resid + (size_t)blockIdx.z * dz;
          size_t idx = (size_t)m * ldd + n;
          D[idx] = val + R[idx];
        } else {
          ((u16*)Dp)[(size_t)m * ldd + n] = f2bf(val);
        }
      }
    }
  }
}

// ---------------- fused attention (no-max softmax, j-split partials) --------
// grid (128 i-blocks of 32 rows, 2 j-chunks of 2048, 2 batches), 512 threads.
// All 8 waves share the 32 Q-rows (L1-resident 32KB Q block).
// QK^T: wave w covers tokens w*64..w*64+64 of the 512-token jt tile.
// PV:   wave w covers channels w*64..w*64+64, K = the full 512-token jt tile.
// q,k token-major [8192][512]; v channel-major [512][8192].
__global__ __launch_bounds__(512, 4) void attn_kernel(
    const u16* __restrict__ q, const u16* __restrict__ k,
    const u16* __restrict__ v, float* __restrict__ Opart,
    float* __restrict__ rspart)
{
  const int t = threadIdx.x;
  const int wv = t >> 6, l = t & 63, lr = l & 15, lq = l >> 4;
  const int i0 = blockIdx.x * 32, jc = blockIdx.y, b = blockIdx.z;

  __shared__ u16 Ps[32][520];     // +8 pad: b128 reads hit the 8-cycle floor
  __shared__ float rsred[8][32];

  f32x4 oacc[2][4] = {};          // rows rf*16+.., ch wv*64 + cf*16 + lr
  float rs_acc[2][4] = {};
  const float SCL2 = 0.06376774487989831f;  // log2(e)/sqrt(512)

  const size_t qbase = (size_t)(b * HW_ + i0) * C_ + lq * 8;

  for (int jt = 0; jt < 4; ++jt) {
    const int j0 = jc * 2048 + jt * 512;
    // ---- scores: per-wave 32 rows x 64 tokens over K=512 ----
    const size_t krow = (size_t)(b * HW_ + j0 + wv * 64 + lr) * C_ + lq * 8;
    f32x4 s[2][4] = {};
    #pragma unroll 4
    for (int k0 = 0; k0 < 512; k0 += 32) {
      bf16x8 aq[2], bk[4];
      #pragma unroll
      for (int rf = 0; rf < 2; ++rf)
        aq[rf] = *(const bf16x8*)(q + qbase + (size_t)(rf * 16 + lr) * C_ + k0);
      #pragma unroll
      for (int cf = 0; cf < 4; ++cf)
        bk[cf] = *(const bf16x8*)(k + krow + (size_t)cf * (16 * C_) + k0);
      #pragma unroll
      for (int rf = 0; rf < 2; ++rf)
        #pragma unroll
        for (int cf = 0; cf < 4; ++cf)
          s[rf][cf] = MFMA16(aq[rf], bk[cf], s[rf][cf], 0, 0, 0);
    }
    // ---- exp, rowsum partial (shfl butterfly over lr), Ps write ----
    #pragma unroll
    for (int rf = 0; rf < 2; ++rf) {
      #pragma unroll
      for (int reg = 0; reg < 4; ++reg) {
        float rsum = 0.0f;
        #pragma unroll
        for (int cf = 0; cf < 4; ++cf) {
          float p = exp2f(s[rf][cf][reg] * SCL2);
          s[rf][cf][reg] = p;
          rsum += p;
        }
        rsum += __shfl_xor(rsum, 1);
        rsum += __shfl_xor(rsum, 2);
        rsum += __shfl_xor(rsum, 4);
        rsum += __shfl_xor(rsum, 8);
        rs_acc[rf][reg] += rsum;
        const int prow = rf * 16 + lq * 4 + reg;
        #pragma unroll
        for (int cf = 0; cf < 4; ++cf)
          Ps[prow][wv * 64 + cf * 16 + lr] = f2bf(s[rf][cf][reg]);
      }
    }
    __syncthreads();
    // ---- PV: per-wave 32 rows x 64 ch, K = 512 tokens (this jt tile) ----
    const size_t vbase = (size_t)(wv * 64 + lr) * NTOK + b * HW_ + j0 + lq * 8;
    #pragma unroll 4
    for (int js = 0; js < 16; ++js) {
      bf16x8 ap[2], vb[4];
      #pragma unroll
      for (int rf = 0; rf < 2; ++rf)
        ap[rf] = *(const bf16x8*)&Ps[rf * 16 + lr][js * 32 + lq * 8];
      #pragma unroll
      for (int cf = 0; cf < 4; ++cf)
        vb[cf] = *(const bf16x8*)(v + vbase + (size_t)cf * (16 * NTOK) + js * 32);
      #pragma unroll
      for (int rf = 0; rf < 2; ++rf)
        #pragma unroll
        for (int cf = 0; cf < 4; ++cf)
          oacc[rf][cf] = MFMA16(ap[rf], vb[cf], oacc[rf][cf], 0, 0, 0);
    }
    __syncthreads();
  }
  // ---- rowsum partials: cross-wave reduce, one value per row ----
  if (lr == 0) {
    #pragma unroll
    for (int rf = 0; rf < 2; ++rf)
      #pragma unroll
      for (int reg = 0; reg < 4; ++reg)
        rsred[wv][rf * 16 + lq * 4 + reg] = rs_acc[rf][reg];
  }
  __syncthreads();
  if (wv == 0 && l < 32) {
    const int row = l;
    float tot = 0.0f;
    #pragma unroll
    for (int w = 0; w < 8; ++w) tot += rsred[w][row];
    rspart[(size_t)jc * NTOK + b * HW_ + i0 + row] = tot;
  }
  // ---- unnormalized O partial (fp32, token-major) ----
  #pragma unroll
  for (int rf = 0; rf < 2; ++rf) {
    #pragma unroll
    for (int reg = 0; reg < 4; ++reg) {
      const size_t orow = ((size_t)jc * NTOK + b * HW_ + i0 + rf * 16 + lq * 4 + reg) * C_ + wv * 64;
      #pragma unroll
      for (int cf = 0; cf < 4; ++cf)
        Opart[orow + cf * 16 + lr] = oacc[rf][cf][reg];
    }
  }
}

// ---------------- combine the 2 j-chunk partials, normalize, -> bf16 --------
__global__ __launch_bounds__(256) void combine_kernel(const float* __restrict__ Opart,
                                                      const float* __restrict__ rspart,
                                                      u16* __restrict__ ao) {
  const size_t idx4 = ((size_t)blockIdx.x * 256 + threadIdx.x) * 4;  // < 8192*512
  const int tok = (int)(idx4 >> 9);
  const float inv = 1.0f / (rspart[tok] + rspart[NTOK + tok]);
  f32x4 a  = *(const f32x4*)(Opart + idx4);
  f32x4 b2 = *(const f32x4*)(Opart + (size_t)NTOK * C_ + idx4);
  ushort4 o;
  o.x = f2bf((a.x + b2.x) * inv);
  o.y = f2bf((a.y + b2.y) * inv);
  o.z = f2bf((a.z + b2.z) * inv);
  o.w = f2bf((a.w + b2.w) * inv);
  *(ushort4*)(ao + idx4) = o;
}

extern "C" void kernel_launch(void* const* d_in, const int* in_sizes, int n_in,
                              void* d_out, int out_size, void* d_ws, size_t ws_size,
                              hipStream_t stream) {
  const float* x   = (const float*)d_in[0];
  const float* gnw = (const float*)d_in[1];
  const float* gnb = (const float*)d_in[2];
  const float* qw  = (const float*)d_in[3];
  const float* qb  = (const float*)d_in[4];
  const float* kw  = (const float*)d_in[5];
  const float* kb  = (const float*)d_in[6];
  const float* vw  = (const float*)d_in[7];
  const float* vb  = (const float*)d_in[8];
  const float* pw  = (const float*)d_in[9];
  const float* pb  = (const float*)d_in[10];

  // workspace layout (77,660,672 bytes total, all 256B-aligned)
  char* ws = (char*)d_ws;
  u16*   wqb   = (u16*)(ws + 0);             //  512*512 bf16 x4
  u16*   wkb   = wqb + 262144;
  u16*   wvb   = wkb + 262144;
  u16*   wpb   = wvb + 262144;
  float* gstat = (float*)(ws + 2097152);     //  64 x (mean, rstd)
  u16*   hT    = (u16*)(ws + 2097664);       //  [8192][512] bf16
  u16*   qm    = (u16*)(ws + 10486272);      //  [8192][512] bf16
  u16*   km    = (u16*)(ws + 18874880);      //  [8192][512] bf16
  u16*   vm    = (u16*)(ws + 27263488);      //  [512][8192] bf16
  u16*   ao    = (u16*)(ws + 35652096);      //  [8192][512] bf16
  float* Opart = (float*)(ws + 44040704);    //  [2][8192][512] f32
  float* rsp   = (float*)(ws + 77595136);    //  [2][8192] f32

  wcast_kernel<<<1024, 256, 0, stream>>>(qw, kw, vw, pw, wqb);
  gn_stats_kernel<<<64, 256, 0, stream>>>(x, gstat);
  gn_apply_kernel<<<dim3(64, 8, 2), 256, 0, stream>>>(x, gnw, gnb, gstat, hT);
  // q, k: token-major, bias per-n
  gemm_abt<1, 0><<<dim3(128, 8), 256, 0, stream>>>(hT, 512, wqb, 512, 0, qb, nullptr, qm, 512, 0, 512);
  gemm_abt<1, 0><<<dim3(128, 8), 256, 0, stream>>>(hT, 512, wkb, 512, 0, kb, nullptr, km, 512, 0, 512);
  // v: channel-major, bias per-m
  gemm_abt<0, 0><<<dim3(8, 128), 256, 0, stream>>>(wvb, 512, hT, 512, 0, vb, nullptr, vm, 8192, 0, 512);
  attn_kernel<<<dim3(128, 2, 2), 512, 0, stream>>>(qm, km, vm, Opart, rsp);
  combine_kernel<<<4096, 256, 0, stream>>>(Opart, rsp, ao);
  // proj + bias + residual, fp32 out, per-batch via blockIdx.z
  gemm_abt<0, 1><<<dim3(8, 64, 2), 256, 0, stream>>>(wpb, 512, ao, 512, 2097152L, pb, x, d_out, 4096, 2097152L, 512);
}

// Round 3
// 279.472 us; speedup vs baseline: 1.4133x; 1.3489x over previous
//
#include <hip/hip_runtime.h>

#define C_   512
#define HW_  4096
#define NTOK 8192

typedef __attribute__((ext_vector_type(8))) short bf16x8;
typedef __attribute__((ext_vector_type(4))) float f32x4;
typedef unsigned short u16;

#define MFMA16 __builtin_amdgcn_mfma_f32_16x16x32_bf16

__device__ __forceinline__ u16 f2bf(float f) {
  unsigned int u = __float_as_uint(f);
  u += 0x7fffu + ((u >> 16) & 1u);
  return (u16)(u >> 16);
}

__device__ __forceinline__ void gld_lds16(const u16* g, u16* l) {
  __builtin_amdgcn_global_load_lds(
      (const __attribute__((address_space(1))) void*)g,
      (__attribute__((address_space(3))) void*)l, 16, 0, 0);
}

// ---------------- weight fp32 -> bf16 cast (4 matrices of 512x512) ----------
__global__ void wcast_kernel(const float* __restrict__ a, const float* __restrict__ b,
                             const float* __restrict__ c, const float* __restrict__ d,
                             u16* __restrict__ out) {
  int gid = blockIdx.x * 256 + threadIdx.x;   // 262144 threads, 4 floats each
  int which = gid >> 16;
  const float* src = which == 0 ? a : which == 1 ? b : which == 2 ? c : d;
  int loc = (gid & 65535) * 4;
  float4 v = *(const float4*)(src + loc);
  ushort4 o;
  o.x = f2bf(v.x); o.y = f2bf(v.y); o.z = f2bf(v.z); o.w = f2bf(v.w);
  *(ushort4*)(out + ((size_t)which << 18) + loc) = o;
}

// ---------------- GroupNorm stats: one block per (batch, group) -------------
__global__ __launch_bounds__(256) void gn_stats_kernel(const float* __restrict__ x,
                                                       float* __restrict__ gstat) {
  const int blk = blockIdx.x;  // b*32+g, slice is contiguous 65536 floats
  const float4* p = (const float4*)(x + (size_t)blk * 65536);
  float s = 0.0f, ss = 0.0f;
  for (int i = threadIdx.x; i < 16384; i += 256) {
    float4 v = p[i];
    s  += v.x + v.y + v.z + v.w;
    ss += v.x * v.x + v.y * v.y + v.z * v.z + v.w * v.w;
  }
  #pragma unroll
  for (int m = 1; m < 64; m <<= 1) { s += __shfl_xor(s, m); ss += __shfl_xor(ss, m); }
  __shared__ float rs[4], rss[4];
  const int wv = threadIdx.x >> 6;
  if ((threadIdx.x & 63) == 0) { rs[wv] = s; rss[wv] = ss; }
  __syncthreads();
  if (threadIdx.x == 0) {
    float S  = rs[0] + rs[1] + rs[2] + rs[3];
    float SS = rss[0] + rss[1] + rss[2] + rss[3];
    float mean = S * (1.0f / 65536.0f);
    float var  = fmaxf(SS * (1.0f / 65536.0f) - mean * mean, 0.0f);
    gstat[2 * blk]     = mean;
    gstat[2 * blk + 1] = rsqrtf(var + 1e-6f);
  }
}

// ---------------- GN apply + transpose to token-major bf16 hT[8192][512] ----
__global__ __launch_bounds__(256) void gn_apply_kernel(const float* __restrict__ x,
                                                       const float* __restrict__ gnw,
                                                       const float* __restrict__ gnb,
                                                       const float* __restrict__ gstat,
                                                       u16* __restrict__ hT) {
  const int b = blockIdx.z, c0 = blockIdx.y * 64, hw0 = blockIdx.x * 64;
  const int t = threadIdx.x;
  __shared__ float tile[64][65];
  {
    const int tx = t & 63, ty = t >> 6;  // ty 0..3
    #pragma unroll
    for (int i = 0; i < 16; ++i) {
      int cl = ty * 16 + i;
      int c = c0 + cl;
      int g = b * 32 + (c >> 4);
      float mean = gstat[2 * g], rstd = gstat[2 * g + 1];
      float val = x[((size_t)(b * C_ + c)) * HW_ + hw0 + tx];
      tile[cl][tx] = (val - mean) * rstd * gnw[c] + gnb[c];
    }
  }
  __syncthreads();
  {
    const int cx = (t & 31) * 2, ty = t >> 5;  // ty 0..7
    #pragma unroll
    for (int i = 0; i < 8; ++i) {
      int hwl = ty * 8 + i;
      unsigned pk = (unsigned)f2bf(tile[cx][hwl]) | ((unsigned)f2bf(tile[cx + 1][hwl]) << 16);
      *(unsigned*)&hT[((size_t)(b * HW_ + hw0 + hwl)) * C_ + c0 + cx] = pk;
    }
  }
}

// ---------------- generic bf16 A(MxK) @ B(NxK)^T GEMM, 64x64 tile -----------
// BIAS_N: bias indexed by n (else by m). RESID: fp32 out + residual add.
template<int BIAS_N, int RESID>
__global__ __launch_bounds__(256, 4) void gemm_abt(
    const u16* __restrict__ A, int lda,
    const u16* __restrict__ B, int ldb, long bz,
    const float* __restrict__ bias,
    const float* __restrict__ resid,
    void* __restrict__ Dp, int ldd, long dz, int K)
{
  B += (size_t)blockIdx.z * (size_t)bz;
  const int t = threadIdx.x;
  const int m0 = blockIdx.x * 64, n0 = blockIdx.y * 64;
  const int wv = t >> 6, l = t & 63, lr = l & 15, lq = l >> 4;
  const int ro = (wv >> 1) * 32, co = (wv & 1) * 32;
  __shared__ u16 As[64][72];
  __shared__ u16 Bs[64][72];
  f32x4 acc[2][2] = {};
  const int ldr_ = t >> 2;
  const int ldc_ = (t & 3) * 16;
  for (int k0 = 0; k0 < K; k0 += 64) {
    *(uint4*)&As[ldr_][ldc_]     = *(const uint4*)(A + (size_t)(m0 + ldr_) * lda + k0 + ldc_);
    *(uint4*)&As[ldr_][ldc_ + 8] = *(const uint4*)(A + (size_t)(m0 + ldr_) * lda + k0 + ldc_ + 8);
    *(uint4*)&Bs[ldr_][ldc_]     = *(const uint4*)(B + (size_t)(n0 + ldr_) * ldb + k0 + ldc_);
    *(uint4*)&Bs[ldr_][ldc_ + 8] = *(const uint4*)(B + (size_t)(n0 + ldr_) * ldb + k0 + ldc_ + 8);
    __syncthreads();
    #pragma unroll
    for (int kk = 0; kk < 64; kk += 32) {
      bf16x8 a0 = *(const bf16x8*)&As[ro + lr][kk + lq * 8];
      bf16x8 a1 = *(const bf16x8*)&As[ro + 16 + lr][kk + lq * 8];
      bf16x8 b0 = *(const bf16x8*)&Bs[co + lr][kk + lq * 8];
      bf16x8 b1 = *(const bf16x8*)&Bs[co + 16 + lr][kk + lq * 8];
      acc[0][0] = MFMA16(a0, b0, acc[0][0], 0, 0, 0);
      acc[0][1] = MFMA16(a0, b1, acc[0][1], 0, 0, 0);
      acc[1][0] = MFMA16(a1, b0, acc[1][0], 0, 0, 0);
      acc[1][1] = MFMA16(a1, b1, acc[1][1], 0, 0, 0);
    }
    __syncthreads();
  }
  #pragma unroll
  for (int rf = 0; rf < 2; ++rf) {
    #pragma unroll
    for (int cf = 0; cf < 2; ++cf) {
      const int n = n0 + co + cf * 16 + lr;
      const float bn = BIAS_N ? bias[n] : 0.0f;
      #pragma unroll
      for (int reg = 0; reg < 4; ++reg) {
        const int m = m0 + ro + rf * 16 + lq * 4 + reg;
        float val = acc[rf][cf][reg] + (BIAS_N ? bn : bias[m]);
        if (RESID) {
          float* D = (float*)Dp + (size_t)blockIdx.z * dz;
          const float* R = resid + (size_t)blockIdx.z * dz;
          size_t idx = (size_t)m * ldd + n;
          D[idx] = val + R[idx];
        } else {
          ((u16*)Dp)[(size_t)m * ldd + n] = f2bf(val);
        }
      }
    }
  }
}

// ---------------- S-GEMM + exp + rowsum partials (m97 structure) ------------
// Per batch. A=qm[b] [4096][512], B=km[b] [4096][512]. Tile 128x128, BK=64.
// Writes Pexp[4096][4096] bf16 and rsp[jgrp=0..63][8192] rowsum partials.
__global__ __launch_bounds__(256, 2) void sgemm_exp_kernel(
    const u16* __restrict__ A, const u16* __restrict__ B,
    u16* __restrict__ Pexp, float* __restrict__ rsp, int gi0)
{
  const int t = threadIdx.x;
  const int m0 = blockIdx.x * 128, n0 = blockIdx.y * 128;
  const int wv = t >> 6, l = t & 63, lr = l & 15, lq = l >> 4;
  const int wr = wv >> 1, wc = wv & 1;       // 2x2 waves of 64x64
  __shared__ u16 As[128][64];
  __shared__ u16 Bs[128][64];
  f32x4 acc[4][4] = {};
  for (int k0 = 0; k0 < 512; k0 += 64) {
    #pragma unroll
    for (int it = 0; it < 4; ++it) {
      const int ci = it * 256 + t;           // 1024 chunks of 16B
      const int row = ci >> 3, c8 = (ci & 7) * 8;
      gld_lds16(A + (size_t)(m0 + row) * 512 + k0 + c8, &As[0][0] + ci * 8);
      gld_lds16(B + (size_t)(n0 + row) * 512 + k0 + c8, &Bs[0][0] + ci * 8);
    }
    __syncthreads();
    #pragma unroll
    for (int kk = 0; kk < 64; kk += 32) {
      bf16x8 af[4], bf[4];
      #pragma unroll
      for (int fr = 0; fr < 4; ++fr)
        af[fr] = *(const bf16x8*)&As[wr * 64 + fr * 16 + lr][kk + lq * 8];
      #pragma unroll
      for (int fc = 0; fc < 4; ++fc)
        bf[fc] = *(const bf16x8*)&Bs[wc * 64 + fc * 16 + lr][kk + lq * 8];
      #pragma unroll
      for (int fr = 0; fr < 4; ++fr)
        #pragma unroll
        for (int fc = 0; fc < 4; ++fc)
          acc[fr][fc] = MFMA16(af[fr], bf[fc], acc[fr][fc], 0, 0, 0);
    }
    __syncthreads();
  }
  // epilogue: exp2(s*scale), rowsum partial over this wave's 64 cols, stores
  const float SCL2 = 0.06376774487989831f;   // log2(e)/sqrt(512)
  #pragma unroll
  for (int fr = 0; fr < 4; ++fr) {
    #pragma unroll
    for (int reg = 0; reg < 4; ++reg) {
      float rsum = 0.0f;
      const int row = m0 + wr * 64 + fr * 16 + lq * 4 + reg;
      u16* prow = Pexp + (size_t)row * 4096 + n0 + wc * 64 + lr;
      #pragma unroll
      for (int fc = 0; fc < 4; ++fc) {
        float p = exp2f(acc[fr][fc][reg] * SCL2);
        rsum += p;
        prow[fc * 16] = f2bf(p);
      }
      rsum += __shfl_xor(rsum, 1);
      rsum += __shfl_xor(rsum, 2);
      rsum += __shfl_xor(rsum, 4);
      rsum += __shfl_xor(rsum, 8);
      if (lr == 0)
        rsp[(size_t)(blockIdx.y * 2 + wc) * NTOK + gi0 + row] = rsum;
    }
  }
}

// ---------------- rowsum reduce: rinv[i] = 1/sum_j rsp[j][i] ----------------
__global__ __launch_bounds__(512) void rs_reduce_kernel(const float* __restrict__ rsp,
                                                        float* __restrict__ rinv, int gi0) {
  const int i = gi0 + blockIdx.x * 512 + threadIdx.x;
  float s = 0.0f;
  #pragma unroll 8
  for (int jg = 0; jg < 64; ++jg) s += rsp[(size_t)jg * NTOK + i];
  rinv[i] = 1.0f / s;
}

// ---------------- PV GEMM: O = Pexp @ V^T, scale by rinv, -> ao bf16 --------
// Per batch. A=Pexp [4096][4096]; B=vm[b] channel-major rows [512][tok].
// Tile 128x64, BK=64, K=4096. 4 waves stacked on rows (32 each).
__global__ __launch_bounds__(256, 2) void pvgemm_kernel(
    const u16* __restrict__ A, const u16* __restrict__ B,
    const float* __restrict__ rinv, u16* __restrict__ ao)
{
  const int t = threadIdx.x;
  const int m0 = blockIdx.x * 128, n0 = blockIdx.y * 64;
  const int wv = t >> 6, l = t & 63, lr = l & 15, lq = l >> 4;
  __shared__ u16 As[128][64];
  __shared__ u16 Bs[64][64];
  f32x4 acc[2][4] = {};
  for (int k0 = 0; k0 < 4096; k0 += 64) {
    #pragma unroll
    for (int it = 0; it < 4; ++it) {
      const int ci = it * 256 + t;
      gld_lds16(A + (size_t)(m0 + (ci >> 3)) * 4096 + k0 + (ci & 7) * 8, &As[0][0] + ci * 8);
    }
    #pragma unroll
    for (int it = 0; it < 2; ++it) {
      const int ci = it * 256 + t;
      gld_lds16(B + (size_t)(n0 + (ci >> 3)) * NTOK + k0 + (ci & 7) * 8, &Bs[0][0] + ci * 8);
    }
    __syncthreads();
    #pragma unroll
    for (int kk = 0; kk < 64; kk += 32) {
      bf16x8 af[2], bf[4];
      #pragma unroll
      for (int fr = 0; fr < 2; ++fr)
        af[fr] = *(const bf16x8*)&As[wv * 32 + fr * 16 + lr][kk + lq * 8];
      #pragma unroll
      for (int fc = 0; fc < 4; ++fc)
        bf[fc] = *(const bf16x8*)&Bs[fc * 16 + lr][kk + lq * 8];
      #pragma unroll
      for (int fr = 0; fr < 2; ++fr)
        #pragma unroll
        for (int fc = 0; fc < 4; ++fc)
          acc[fr][fc] = MFMA16(af[fr], bf[fc], acc[fr][fc], 0, 0, 0);
    }
    __syncthreads();
  }
  #pragma unroll
  for (int fr = 0; fr < 2; ++fr) {
    #pragma unroll
    for (int reg = 0; reg < 4; ++reg) {
      const int m = m0 + wv * 32 + fr * 16 + lq * 4 + reg;
      const float ri = rinv[m];
      u16* orow = ao + (size_t)m * 512 + n0 + lr;
      #pragma unroll
      for (int fc = 0; fc < 4; ++fc)
        orow[fc * 16] = f2bf(acc[fr][fc][reg] * ri);
    }
  }
}

extern "C" void kernel_launch(void* const* d_in, const int* in_sizes, int n_in,
                              void* d_out, int out_size, void* d_ws, size_t ws_size,
                              hipStream_t stream) {
  const float* x   = (const float*)d_in[0];
  const float* gnw = (const float*)d_in[1];
  const float* gnb = (const float*)d_in[2];
  const float* qw  = (const float*)d_in[3];
  const float* qb  = (const float*)d_in[4];
  const float* kw  = (const float*)d_in[5];
  const float* kb  = (const float*)d_in[6];
  const float* vw  = (const float*)d_in[7];
  const float* vb  = (const float*)d_in[8];
  const float* pw  = (const float*)d_in[9];
  const float* pb  = (const float*)d_in[10];

  // workspace layout (71,336,448 bytes peak; 77.66MB proven available)
  char* ws = (char*)d_ws;
  u16*   wqb   = (u16*)(ws + 0);             // 4x 512x512 bf16 (2MB)
  u16*   wkb   = wqb + 262144;
  u16*   wvb   = wkb + 262144;
  u16*   wpb   = wvb + 262144;
  float* gstat = (float*)(ws + 2097152);     // 64 x (mean, rstd)
  float* rinv  = (float*)(ws + 2097664);     // [8192] f32
  float* rsp   = (float*)(ws + 2130432);     // [64][8192] f32 (2MB)
  u16*   hT    = (u16*)(ws + 4227584);       // [8192][512] bf16 (8MB), dead after v-GEMM
  u16*   ao    = hT;                         // reuses hT region: [2][4096][512] bf16
  u16*   qm    = (u16*)(ws + 12616192);      // [8192][512] bf16
  u16*   km    = (u16*)(ws + 21004800);      // [8192][512] bf16
  u16*   vm    = (u16*)(ws + 29393408);      // [512][8192] bf16
  u16*   Pexp  = (u16*)(ws + 37782016);      // [4096][4096] bf16 (33.5MB, per-batch reuse)

  wcast_kernel<<<1024, 256, 0, stream>>>(qw, kw, vw, pw, wqb);
  gn_stats_kernel<<<64, 256, 0, stream>>>(x, gstat);
  gn_apply_kernel<<<dim3(64, 8, 2), 256, 0, stream>>>(x, gnw, gnb, gstat, hT);
  // q, k: token-major, bias per-n
  gemm_abt<1, 0><<<dim3(128, 8), 256, 0, stream>>>(hT, 512, wqb, 512, 0, qb, nullptr, qm, 512, 0, 512);
  gemm_abt<1, 0><<<dim3(128, 8), 256, 0, stream>>>(hT, 512, wkb, 512, 0, kb, nullptr, km, 512, 0, 512);
  // v: channel-major, bias per-m
  gemm_abt<0, 0><<<dim3(8, 128), 256, 0, stream>>>(wvb, 512, hT, 512, 0, vb, nullptr, vm, 8192, 0, 512);

  for (int b = 0; b < 2; ++b) {
    const u16* qmb = qm + (size_t)b * HW_ * C_;
    const u16* kmb = km + (size_t)b * HW_ * C_;
    sgemm_exp_kernel<<<dim3(32, 32), 256, 0, stream>>>(qmb, kmb, Pexp, rsp, b * HW_);
    rs_reduce_kernel<<<8, 512, 0, stream>>>(rsp, rinv, b * HW_);
    pvgemm_kernel<<<dim3(32, 8), 256, 0, stream>>>(Pexp, vm + (size_t)b * HW_,
                                                   rinv + b * HW_, ao + (size_t)b * HW_ * C_);
  }
  // proj + bias + residual, fp32 out, per-batch via blockIdx.z
  gemm_abt<0, 1><<<dim3(8, 64, 2), 256, 0, stream>>>(wpb, 512, ao, 512, 2097152L, pb, x, d_out, 4096, 2097152L, 512);
}

// Round 4
// 239.406 us; speedup vs baseline: 1.6498x; 1.1674x over previous
//
#include <hip/hip_runtime.h>

#define C_   512
#define HW_  4096
#define NTOK 8192

typedef __attribute__((ext_vector_type(8))) short bf16x8;
typedef __attribute__((ext_vector_type(4))) float f32x4;
typedef unsigned short u16;

#define MFMA16 __builtin_amdgcn_mfma_f32_16x16x32_bf16

__device__ __forceinline__ u16 f2bf(float f) {
  unsigned int u = __float_as_uint(f);
  u += 0x7fffu + ((u >> 16) & 1u);
  return (u16)(u >> 16);
}

__device__ __forceinline__ float bf2f(u16 v) {
  return __uint_as_float((unsigned)v << 16);
}

__device__ __forceinline__ void gld_lds16(const u16* g, u16* l) {
  __builtin_amdgcn_global_load_lds(
      (const __attribute__((address_space(1))) void*)g,
      (__attribute__((address_space(3))) void*)l, 16, 0, 0);
}

// ---------------- weight fp32 -> bf16 cast (4 matrices of 512x512) ----------
__global__ void wcast_kernel(const float* __restrict__ a, const float* __restrict__ b,
                             const float* __restrict__ c, const float* __restrict__ d,
                             u16* __restrict__ out) {
  int gid = blockIdx.x * 256 + threadIdx.x;   // 262144 threads, 4 floats each
  int which = gid >> 16;
  const float* src = which == 0 ? a : which == 1 ? b : which == 2 ? c : d;
  int loc = (gid & 65535) * 4;
  float4 v = *(const float4*)(src + loc);
  ushort4 o;
  o.x = f2bf(v.x); o.y = f2bf(v.y); o.z = f2bf(v.z); o.w = f2bf(v.w);
  *(ushort4*)(out + ((size_t)which << 18) + loc) = o;
}

// ---------------- GroupNorm stats: one block per (batch, group) -------------
__global__ __launch_bounds__(256) void gn_stats_kernel(const float* __restrict__ x,
                                                       float* __restrict__ gstat) {
  const int blk = blockIdx.x;  // b*32+g, slice is contiguous 65536 floats
  const float4* p = (const float4*)(x + (size_t)blk * 65536);
  float s = 0.0f, ss = 0.0f;
  for (int i = threadIdx.x; i < 16384; i += 256) {
    float4 v = p[i];
    s  += v.x + v.y + v.z + v.w;
    ss += v.x * v.x + v.y * v.y + v.z * v.z + v.w * v.w;
  }
  #pragma unroll
  for (int m = 1; m < 64; m <<= 1) { s += __shfl_xor(s, m); ss += __shfl_xor(ss, m); }
  __shared__ float rs[4], rss[4];
  const int wv = threadIdx.x >> 6;
  if ((threadIdx.x & 63) == 0) { rs[wv] = s; rss[wv] = ss; }
  __syncthreads();
  if (threadIdx.x == 0) {
    float S  = rs[0] + rs[1] + rs[2] + rs[3];
    float SS = rss[0] + rss[1] + rss[2] + rss[3];
    float mean = S * (1.0f / 65536.0f);
    float var  = fmaxf(SS * (1.0f / 65536.0f) - mean * mean, 0.0f);
    gstat[2 * blk]     = mean;
    gstat[2 * blk + 1] = rsqrtf(var + 1e-6f);
  }
}

// ---------------- GN apply + transpose to token-major bf16 hT[8192][512] ----
__global__ __launch_bounds__(256) void gn_apply_kernel(const float* __restrict__ x,
                                                       const float* __restrict__ gnw,
                                                       const float* __restrict__ gnb,
                                                       const float* __restrict__ gstat,
                                                       u16* __restrict__ hT) {
  const int b = blockIdx.z, c0 = blockIdx.y * 64, hw0 = blockIdx.x * 64;
  const int t = threadIdx.x;
  __shared__ float tile[64][65];
  {
    const int tx = t & 63, ty = t >> 6;  // ty 0..3
    #pragma unroll
    for (int i = 0; i < 16; ++i) {
      int cl = ty * 16 + i;
      int c = c0 + cl;
      int g = b * 32 + (c >> 4);
      float mean = gstat[2 * g], rstd = gstat[2 * g + 1];
      float val = x[((size_t)(b * C_ + c)) * HW_ + hw0 + tx];
      tile[cl][tx] = (val - mean) * rstd * gnw[c] + gnb[c];
    }
  }
  __syncthreads();
  {
    const int cx = (t & 31) * 2, ty = t >> 5;  // ty 0..7
    #pragma unroll
    for (int i = 0; i < 8; ++i) {
      int hwl = ty * 8 + i;
      unsigned pk = (unsigned)f2bf(tile[cx][hwl]) | ((unsigned)f2bf(tile[cx + 1][hwl]) << 16);
      *(unsigned*)&hT[((size_t)(b * HW_ + hw0 + hwl)) * C_ + c0 + cx] = pk;
    }
  }
}

// ---------------- generic bf16 A(MxK) @ B(NxK)^T GEMM, 64x64 tile -----------
// BIAS_N: bias indexed by n (else by m). RESID: fp32 out + residual add.
template<int BIAS_N, int RESID>
__global__ __launch_bounds__(256, 4) void gemm_abt(
    const u16* __restrict__ A, int lda,
    const u16* __restrict__ B, int ldb, long bz,
    const float* __restrict__ bias,
    const float* __restrict__ resid,
    void* __restrict__ Dp, int ldd, long dz, int K)
{
  B += (size_t)blockIdx.z * (size_t)bz;
  const int t = threadIdx.x;
  const int m0 = blockIdx.x * 64, n0 = blockIdx.y * 64;
  const int wv = t >> 6, l = t & 63, lr = l & 15, lq = l >> 4;
  const int ro = (wv >> 1) * 32, co = (wv & 1) * 32;
  __shared__ u16 As[64][72];
  __shared__ u16 Bs[64][72];
  f32x4 acc[2][2] = {};
  const int ldr_ = t >> 2;
  const int ldc_ = (t & 3) * 16;
  for (int k0 = 0; k0 < K; k0 += 64) {
    *(uint4*)&As[ldr_][ldc_]     = *(const uint4*)(A + (size_t)(m0 + ldr_) * lda + k0 + ldc_);
    *(uint4*)&As[ldr_][ldc_ + 8] = *(const uint4*)(A + (size_t)(m0 + ldr_) * lda + k0 + ldc_ + 8);
    *(uint4*)&Bs[ldr_][ldc_]     = *(const uint4*)(B + (size_t)(n0 + ldr_) * ldb + k0 + ldc_);
    *(uint4*)&Bs[ldr_][ldc_ + 8] = *(const uint4*)(B + (size_t)(n0 + ldr_) * ldb + k0 + ldc_ + 8);
    __syncthreads();
    #pragma unroll
    for (int kk = 0; kk < 64; kk += 32) {
      bf16x8 a0 = *(const bf16x8*)&As[ro + lr][kk + lq * 8];
      bf16x8 a1 = *(const bf16x8*)&As[ro + 16 + lr][kk + lq * 8];
      bf16x8 b0 = *(const bf16x8*)&Bs[co + lr][kk + lq * 8];
      bf16x8 b1 = *(const bf16x8*)&Bs[co + 16 + lr][kk + lq * 8];
      acc[0][0] = MFMA16(a0, b0, acc[0][0], 0, 0, 0);
      acc[0][1] = MFMA16(a0, b1, acc[0][1], 0, 0, 0);
      acc[1][0] = MFMA16(a1, b0, acc[1][0], 0, 0, 0);
      acc[1][1] = MFMA16(a1, b1, acc[1][1], 0, 0, 0);
    }
    __syncthreads();
  }
  #pragma unroll
  for (int rf = 0; rf < 2; ++rf) {
    #pragma unroll
    for (int cf = 0; cf < 2; ++cf) {
      const int n = n0 + co + cf * 16 + lr;
      const float bn = BIAS_N ? bias[n] : 0.0f;
      #pragma unroll
      for (int reg = 0; reg < 4; ++reg) {
        const int m = m0 + ro + rf * 16 + lq * 4 + reg;
        float val = acc[rf][cf][reg] + (BIAS_N ? bn : bias[m]);
        if (RESID) {
          float* D = (float*)Dp + (size_t)blockIdx.z * dz;
          const float* R = resid + (size_t)blockIdx.z * dz;
          size_t idx = (size_t)m * ldd + n;
          D[idx] = val + R[idx];
        } else {
          ((u16*)Dp)[(size_t)m * ldd + n] = f2bf(val);
        }
      }
    }
  }
}

// ---------------- S-GEMM + exp + rowsum partials (m97 structure) ------------
// Per batch. A=qm[b] [4096][512], B=km[b] [4096][512]. Tile 128x128, BK=64.
// Writes Pexp[4096][4096] bf16 and rsp[jgrp=0..63][8192] rowsum partials.
__global__ __launch_bounds__(256, 2) void sgemm_exp_kernel(
    const u16* __restrict__ A, const u16* __restrict__ B,
    u16* __restrict__ Pexp, float* __restrict__ rsp, int gi0)
{
  const int t = threadIdx.x;
  const int m0 = blockIdx.x * 128, n0 = blockIdx.y * 128;
  const int wv = t >> 6, l = t & 63, lr = l & 15, lq = l >> 4;
  const int wr = wv >> 1, wc = wv & 1;       // 2x2 waves of 64x64
  __shared__ u16 As[128][64];
  __shared__ u16 Bs[128][64];
  f32x4 acc[4][4] = {};
  for (int k0 = 0; k0 < 512; k0 += 64) {
    #pragma unroll
    for (int it = 0; it < 4; ++it) {
      const int ci = it * 256 + t;           // 1024 chunks of 16B
      const int row = ci >> 3, c8 = (ci & 7) * 8;
      gld_lds16(A + (size_t)(m0 + row) * 512 + k0 + c8, &As[0][0] + ci * 8);
      gld_lds16(B + (size_t)(n0 + row) * 512 + k0 + c8, &Bs[0][0] + ci * 8);
    }
    __syncthreads();
    #pragma unroll
    for (int kk = 0; kk < 64; kk += 32) {
      bf16x8 af[4], bf[4];
      #pragma unroll
      for (int fr = 0; fr < 4; ++fr)
        af[fr] = *(const bf16x8*)&As[wr * 64 + fr * 16 + lr][kk + lq * 8];
      #pragma unroll
      for (int fc = 0; fc < 4; ++fc)
        bf[fc] = *(const bf16x8*)&Bs[wc * 64 + fc * 16 + lr][kk + lq * 8];
      #pragma unroll
      for (int fr = 0; fr < 4; ++fr)
        #pragma unroll
        for (int fc = 0; fc < 4; ++fc)
          acc[fr][fc] = MFMA16(af[fr], bf[fc], acc[fr][fc], 0, 0, 0);
    }
    __syncthreads();
  }
  // epilogue: exp2(s*scale), rowsum partial over this wave's 64 cols, stores
  const float SCL2 = 0.06376774487989831f;   // log2(e)/sqrt(512)
  #pragma unroll
  for (int fr = 0; fr < 4; ++fr) {
    #pragma unroll
    for (int reg = 0; reg < 4; ++reg) {
      float rsum = 0.0f;
      const int row = m0 + wr * 64 + fr * 16 + lq * 4 + reg;
      u16* prow = Pexp + (size_t)row * 4096 + n0 + wc * 64 + lr;
      #pragma unroll
      for (int fc = 0; fc < 4; ++fc) {
        float p = exp2f(acc[fr][fc][reg] * SCL2);
        rsum += p;
        prow[fc * 16] = f2bf(p);
      }
      rsum += __shfl_xor(rsum, 1);
      rsum += __shfl_xor(rsum, 2);
      rsum += __shfl_xor(rsum, 4);
      rsum += __shfl_xor(rsum, 8);
      if (lr == 0)
        rsp[(size_t)(blockIdx.y * 2 + wc) * NTOK + gi0 + row] = rsum;
    }
  }
}

// ---------------- rowsum reduce: rinv[i] = 1/sum_j rsp[j][i] ----------------
__global__ __launch_bounds__(512) void rs_reduce_kernel(const float* __restrict__ rsp,
                                                        float* __restrict__ rinv, int gi0) {
  const int i = gi0 + blockIdx.x * 512 + threadIdx.x;
  float s = 0.0f;
  #pragma unroll 8
  for (int jg = 0; jg < 64; ++jg) s += rsp[(size_t)jg * NTOK + i];
  rinv[i] = 1.0f / s;
}

// ---------------- PV GEMM split-K: Op[sp] = Pexp @ V^T over K-half sp -------
// Per batch. A=Pexp [4096][4096]; B=vm[b] channel-major rows [512][tok].
// Tile 64x64, BK=64, K=2048 per split. grid (64, 8, 2) = 1024 blocks.
__global__ __launch_bounds__(256, 4) void pvgemm_splitk(
    const u16* __restrict__ A, const u16* __restrict__ B,
    u16* __restrict__ Op0, u16* __restrict__ Op1)
{
  const int t = threadIdx.x;
  const int m0 = blockIdx.x * 64, n0 = blockIdx.y * 64;
  const int wv = t >> 6, l = t & 63, lr = l & 15, lq = l >> 4;
  const int wr = wv >> 1, wc = wv & 1;       // 2x2 waves of 32x32
  __shared__ u16 As[64][64];
  __shared__ u16 Bs[64][64];
  f32x4 acc[2][2] = {};
  const int kbeg = blockIdx.z * 2048;
  for (int k0 = kbeg; k0 < kbeg + 2048; k0 += 64) {
    #pragma unroll
    for (int it = 0; it < 2; ++it) {
      const int ci = it * 256 + t;           // 512 chunks of 16B per buffer
      const int row = ci >> 3, c8 = (ci & 7) * 8;
      gld_lds16(A + (size_t)(m0 + row) * 4096 + k0 + c8, &As[0][0] + ci * 8);
      gld_lds16(B + (size_t)(n0 + row) * NTOK + k0 + c8, &Bs[0][0] + ci * 8);
    }
    __syncthreads();
    #pragma unroll
    for (int kk = 0; kk < 64; kk += 32) {
      bf16x8 af[2], bf[2];
      #pragma unroll
      for (int fr = 0; fr < 2; ++fr)
        af[fr] = *(const bf16x8*)&As[wr * 32 + fr * 16 + lr][kk + lq * 8];
      #pragma unroll
      for (int fc = 0; fc < 2; ++fc)
        bf[fc] = *(const bf16x8*)&Bs[wc * 32 + fc * 16 + lr][kk + lq * 8];
      #pragma unroll
      for (int fr = 0; fr < 2; ++fr)
        #pragma unroll
        for (int fc = 0; fc < 2; ++fc)
          acc[fr][fc] = MFMA16(af[fr], bf[fc], acc[fr][fc], 0, 0, 0);
    }
    __syncthreads();
  }
  u16* Op = blockIdx.z ? Op1 : Op0;
  #pragma unroll
  for (int fr = 0; fr < 2; ++fr) {
    #pragma unroll
    for (int reg = 0; reg < 4; ++reg) {
      const int m = m0 + wr * 32 + fr * 16 + lq * 4 + reg;
      u16* orow = Op + (size_t)m * 512 + n0 + wc * 32 + lr;
      #pragma unroll
      for (int fc = 0; fc < 2; ++fc)
        orow[fc * 16] = f2bf(acc[fr][fc][reg]);
    }
  }
}

// ---------------- combine split-K partials, normalize by rinv, -> ao --------
__global__ __launch_bounds__(256) void combine_norm(const u16* __restrict__ Op0,
                                                    const u16* __restrict__ Op1,
                                                    const float* __restrict__ rinv,
                                                    u16* __restrict__ ao) {
  const size_t idx8 = ((size_t)blockIdx.x * 256 + threadIdx.x) * 8;  // < 4096*512
  const float ri = rinv[idx8 >> 9];
  ushort4 a0 = *(const ushort4*)(Op0 + idx8);
  ushort4 a1 = *(const ushort4*)(Op0 + idx8 + 4);
  ushort4 b0 = *(const ushort4*)(Op1 + idx8);
  ushort4 b1 = *(const ushort4*)(Op1 + idx8 + 4);
  ushort4 o0, o1;
  o0.x = f2bf((bf2f(a0.x) + bf2f(b0.x)) * ri);
  o0.y = f2bf((bf2f(a0.y) + bf2f(b0.y)) * ri);
  o0.z = f2bf((bf2f(a0.z) + bf2f(b0.z)) * ri);
  o0.w = f2bf((bf2f(a0.w) + bf2f(b0.w)) * ri);
  o1.x = f2bf((bf2f(a1.x) + bf2f(b1.x)) * ri);
  o1.y = f2bf((bf2f(a1.y) + bf2f(b1.y)) * ri);
  o1.z = f2bf((bf2f(a1.z) + bf2f(b1.z)) * ri);
  o1.w = f2bf((bf2f(a1.w) + bf2f(b1.w)) * ri);
  *(ushort4*)(ao + idx8)     = o0;
  *(ushort4*)(ao + idx8 + 4) = o1;
}

extern "C" void kernel_launch(void* const* d_in, const int* in_sizes, int n_in,
                              void* d_out, int out_size, void* d_ws, size_t ws_size,
                              hipStream_t stream) {
  const float* x   = (const float*)d_in[0];
  const float* gnw = (const float*)d_in[1];
  const float* gnb = (const float*)d_in[2];
  const float* qw  = (const float*)d_in[3];
  const float* qb  = (const float*)d_in[4];
  const float* kw  = (const float*)d_in[5];
  const float* kb  = (const float*)d_in[6];
  const float* vw  = (const float*)d_in[7];
  const float* vb  = (const float*)d_in[8];
  const float* pw  = (const float*)d_in[9];
  const float* pb  = (const float*)d_in[10];

  // workspace layout (71,336,448 bytes peak; 77.66MB proven available)
  char* ws = (char*)d_ws;
  u16*   wqb   = (u16*)(ws + 0);             // 4x 512x512 bf16 (2MB)
  u16*   wkb   = wqb + 262144;
  u16*   wvb   = wkb + 262144;
  u16*   wpb   = wvb + 262144;
  float* gstat = (float*)(ws + 2097152);     // 64 x (mean, rstd)
  float* rinv  = (float*)(ws + 2097664);     // [8192] f32
  float* rsp   = (float*)(ws + 2130432);     // [64][8192] f32 (2MB)
  u16*   hT    = (u16*)(ws + 4227584);       // [8192][512] bf16 (8MB), dead after v-GEMM
  u16*   ao    = hT;                         // reuses hT region: [2][4096][512] bf16
  u16*   qm    = (u16*)(ws + 12616192);      // [8192][512] bf16
  u16*   km    = (u16*)(ws + 21004800);      // [8192][512] bf16
  u16*   vm    = (u16*)(ws + 29393408);      // [512][8192] bf16
  u16*   Pexp  = (u16*)(ws + 37782016);      // [4096][4096] bf16 (33.5MB, per-batch reuse)
  // split-K partials: qm[b0]/km[b0] slices are dead once any pvgemm runs
  u16*   Op0   = qm;                         // [4096][512] bf16 (4MB)
  u16*   Op1   = km;                         // [4096][512] bf16 (4MB)

  wcast_kernel<<<1024, 256, 0, stream>>>(qw, kw, vw, pw, wqb);
  gn_stats_kernel<<<64, 256, 0, stream>>>(x, gstat);
  gn_apply_kernel<<<dim3(64, 8, 2), 256, 0, stream>>>(x, gnw, gnb, gstat, hT);
  // q, k: token-major, bias per-n
  gemm_abt<1, 0><<<dim3(128, 8), 256, 0, stream>>>(hT, 512, wqb, 512, 0, qb, nullptr, qm, 512, 0, 512);
  gemm_abt<1, 0><<<dim3(128, 8), 256, 0, stream>>>(hT, 512, wkb, 512, 0, kb, nullptr, km, 512, 0, 512);
  // v: channel-major, bias per-m
  gemm_abt<0, 0><<<dim3(8, 128), 256, 0, stream>>>(wvb, 512, hT, 512, 0, vb, nullptr, vm, 8192, 0, 512);

  for (int b = 0; b < 2; ++b) {
    const u16* qmb = qm + (size_t)b * HW_ * C_;
    const u16* kmb = km + (size_t)b * HW_ * C_;
    sgemm_exp_kernel<<<dim3(32, 32), 256, 0, stream>>>(qmb, kmb, Pexp, rsp, b * HW_);
    rs_reduce_kernel<<<8, 512, 0, stream>>>(rsp, rinv, b * HW_);
    pvgemm_splitk<<<dim3(64, 8, 2), 256, 0, stream>>>(Pexp, vm + (size_t)b * HW_, Op0, Op1);
    combine_norm<<<1024, 256, 0, stream>>>(Op0, Op1, rinv + b * HW_, ao + (size_t)b * HW_ * C_);
  }
  // proj + bias + residual, fp32 out, per-batch via blockIdx.z
  gemm_abt<0, 1><<<dim3(8, 64, 2), 256, 0, stream>>>(wpb, 512, ao, 512, 2097152L, pb, x, d_out, 4096, 2097152L, 512);
}

// Round 5
// 210.924 us; speedup vs baseline: 1.8725x; 1.1350x over previous
//
#include <hip/hip_runtime.h>

#define C_   512
#define HW_  4096
#define NTOK 8192

typedef __attribute__((ext_vector_type(8))) short bf16x8;
typedef __attribute__((ext_vector_type(4))) float f32x4;
typedef unsigned short u16;

#define MFMA16 __builtin_amdgcn_mfma_f32_16x16x32_bf16

__device__ __forceinline__ u16 f2bf(float f) {
  unsigned int u = __float_as_uint(f);
  u += 0x7fffu + ((u >> 16) & 1u);
  return (u16)(u >> 16);
}

__device__ __forceinline__ float bf2f(u16 v) {
  return __uint_as_float((unsigned)v << 16);
}

__device__ __forceinline__ void gld_lds16(const u16* g, u16* l) {
  __builtin_amdgcn_global_load_lds(
      (const __attribute__((address_space(1))) void*)g,
      (__attribute__((address_space(3))) void*)l, 16, 0, 0);
}

// swizzled LDS chunk address: logical (row, u16-col) -> physical u16 offset.
// Layout: within each row (8 chunks of 16B), chunk o stored at o ^ (row&7).
// Paired with inverse-swizzled global source in the staging loop.
__device__ __forceinline__ const u16* swz(const u16* base, int row, int col, int ldu16) {
  return base + (size_t)row * ldu16 + ((((col >> 3) ^ (row & 7)) << 3) | (col & 7));
}

// ---------------- weight fp32 -> bf16 cast (4 matrices of 512x512) ----------
__global__ void wcast_kernel(const float* __restrict__ a, const float* __restrict__ b,
                             const float* __restrict__ c, const float* __restrict__ d,
                             u16* __restrict__ out) {
  int gid = blockIdx.x * 256 + threadIdx.x;   // 262144 threads, 4 floats each
  int which = gid >> 16;
  const float* src = which == 0 ? a : which == 1 ? b : which == 2 ? c : d;
  int loc = (gid & 65535) * 4;
  float4 v = *(const float4*)(src + loc);
  ushort4 o;
  o.x = f2bf(v.x); o.y = f2bf(v.y); o.z = f2bf(v.z); o.w = f2bf(v.w);
  *(ushort4*)(out + ((size_t)which << 18) + loc) = o;
}

// ---------------- GroupNorm stats: one block per (batch, group) -------------
__global__ __launch_bounds__(256) void gn_stats_kernel(const float* __restrict__ x,
                                                       float* __restrict__ gstat) {
  const int blk = blockIdx.x;  // b*32+g, slice is contiguous 65536 floats
  const float4* p = (const float4*)(x + (size_t)blk * 65536);
  float s = 0.0f, ss = 0.0f;
  for (int i = threadIdx.x; i < 16384; i += 256) {
    float4 v = p[i];
    s  += v.x + v.y + v.z + v.w;
    ss += v.x * v.x + v.y * v.y + v.z * v.z + v.w * v.w;
  }
  #pragma unroll
  for (int m = 1; m < 64; m <<= 1) { s += __shfl_xor(s, m); ss += __shfl_xor(ss, m); }
  __shared__ float rs[4], rss[4];
  const int wv = threadIdx.x >> 6;
  if ((threadIdx.x & 63) == 0) { rs[wv] = s; rss[wv] = ss; }
  __syncthreads();
  if (threadIdx.x == 0) {
    float S  = rs[0] + rs[1] + rs[2] + rs[3];
    float SS = rss[0] + rss[1] + rss[2] + rss[3];
    float mean = S * (1.0f / 65536.0f);
    float var  = fmaxf(SS * (1.0f / 65536.0f) - mean * mean, 0.0f);
    gstat[2 * blk]     = mean;
    gstat[2 * blk + 1] = rsqrtf(var + 1e-6f);
  }
}

// ---------------- GN apply + transpose to token-major bf16 hT[8192][512] ----
__global__ __launch_bounds__(256) void gn_apply_kernel(const float* __restrict__ x,
                                                       const float* __restrict__ gnw,
                                                       const float* __restrict__ gnb,
                                                       const float* __restrict__ gstat,
                                                       u16* __restrict__ hT) {
  const int b = blockIdx.z, c0 = blockIdx.y * 64, hw0 = blockIdx.x * 64;
  const int t = threadIdx.x;
  __shared__ float tile[64][65];
  {
    const int tx = t & 63, ty = t >> 6;  // ty 0..3
    #pragma unroll
    for (int i = 0; i < 16; ++i) {
      int cl = ty * 16 + i;
      int c = c0 + cl;
      int g = b * 32 + (c >> 4);
      float mean = gstat[2 * g], rstd = gstat[2 * g + 1];
      float val = x[((size_t)(b * C_ + c)) * HW_ + hw0 + tx];
      tile[cl][tx] = (val - mean) * rstd * gnw[c] + gnb[c];
    }
  }
  __syncthreads();
  {
    const int cx = (t & 31) * 2, ty = t >> 5;  // ty 0..7
    #pragma unroll
    for (int i = 0; i < 8; ++i) {
      int hwl = ty * 8 + i;
      unsigned pk = (unsigned)f2bf(tile[cx][hwl]) | ((unsigned)f2bf(tile[cx + 1][hwl]) << 16);
      *(unsigned*)&hT[((size_t)(b * HW_ + hw0 + hwl)) * C_ + c0 + cx] = pk;
    }
  }
}

// ---------------- generic bf16 A(MxK) @ B(NxK)^T GEMM, 64x64 tile -----------
// BIAS_N: bias indexed by n (else by m). RESID: fp32 out + residual add.
template<int BIAS_N, int RESID>
__global__ __launch_bounds__(256, 4) void gemm_abt(
    const u16* __restrict__ A, int lda,
    const u16* __restrict__ B, int ldb, long bz,
    const float* __restrict__ bias,
    const float* __restrict__ resid,
    void* __restrict__ Dp, int ldd, long dz, int K)
{
  B += (size_t)blockIdx.z * (size_t)bz;
  const int t = threadIdx.x;
  const int m0 = blockIdx.x * 64, n0 = blockIdx.y * 64;
  const int wv = t >> 6, l = t & 63, lr = l & 15, lq = l >> 4;
  const int ro = (wv >> 1) * 32, co = (wv & 1) * 32;
  __shared__ u16 As[64][72];
  __shared__ u16 Bs[64][72];
  f32x4 acc[2][2] = {};
  const int ldr_ = t >> 2;
  const int ldc_ = (t & 3) * 16;
  for (int k0 = 0; k0 < K; k0 += 64) {
    *(uint4*)&As[ldr_][ldc_]     = *(const uint4*)(A + (size_t)(m0 + ldr_) * lda + k0 + ldc_);
    *(uint4*)&As[ldr_][ldc_ + 8] = *(const uint4*)(A + (size_t)(m0 + ldr_) * lda + k0 + ldc_ + 8);
    *(uint4*)&Bs[ldr_][ldc_]     = *(const uint4*)(B + (size_t)(n0 + ldr_) * ldb + k0 + ldc_);
    *(uint4*)&Bs[ldr_][ldc_ + 8] = *(const uint4*)(B + (size_t)(n0 + ldr_) * ldb + k0 + ldc_ + 8);
    __syncthreads();
    #pragma unroll
    for (int kk = 0; kk < 64; kk += 32) {
      bf16x8 a0 = *(const bf16x8*)&As[ro + lr][kk + lq * 8];
      bf16x8 a1 = *(const bf16x8*)&As[ro + 16 + lr][kk + lq * 8];
      bf16x8 b0 = *(const bf16x8*)&Bs[co + lr][kk + lq * 8];
      bf16x8 b1 = *(const bf16x8*)&Bs[co + 16 + lr][kk + lq * 8];
      acc[0][0] = MFMA16(a0, b0, acc[0][0], 0, 0, 0);
      acc[0][1] = MFMA16(a0, b1, acc[0][1], 0, 0, 0);
      acc[1][0] = MFMA16(a1, b0, acc[1][0], 0, 0, 0);
      acc[1][1] = MFMA16(a1, b1, acc[1][1], 0, 0, 0);
    }
    __syncthreads();
  }
  #pragma unroll
  for (int rf = 0; rf < 2; ++rf) {
    #pragma unroll
    for (int cf = 0; cf < 2; ++cf) {
      const int n = n0 + co + cf * 16 + lr;
      const float bn = BIAS_N ? bias[n] : 0.0f;
      #pragma unroll
      for (int reg = 0; reg < 4; ++reg) {
        const int m = m0 + ro + rf * 16 + lq * 4 + reg;
        float val = acc[rf][cf][reg] + (BIAS_N ? bn : bias[m]);
        if (RESID) {
          float* D = (float*)Dp + (size_t)blockIdx.z * dz;
          const float* R = resid + (size_t)blockIdx.z * dz;
          size_t idx = (size_t)m * ldd + n;
          D[idx] = val + R[idx];
        } else {
          ((u16*)Dp)[(size_t)m * ldd + n] = f2bf(val);
        }
      }
    }
  }
}

// ---------------- S-GEMM + exp + rowsum partials (m97 structure) ------------
// Per batch. A=qm[b] [4096][512], B=km[b] [4096][512]. Tile 128x128, BK=64.
// LDS tiles XOR-swizzled (inverse-swizzled global src + swizzled ds_read).
__global__ __launch_bounds__(256, 2) void sgemm_exp_kernel(
    const u16* __restrict__ A, const u16* __restrict__ B,
    u16* __restrict__ Pexp, float* __restrict__ rsp, int gi0)
{
  const int t = threadIdx.x;
  const int m0 = blockIdx.x * 128, n0 = blockIdx.y * 128;
  const int wv = t >> 6, l = t & 63, lr = l & 15, lq = l >> 4;
  const int wr = wv >> 1, wc = wv & 1;       // 2x2 waves of 64x64
  __shared__ u16 As[128][64];
  __shared__ u16 Bs[128][64];
  f32x4 acc[4][4] = {};
  for (int k0 = 0; k0 < 512; k0 += 64) {
    #pragma unroll
    for (int it = 0; it < 4; ++it) {
      const int ci = it * 256 + t;           // 1024 chunks of 16B
      const int row = ci >> 3;
      const int c8 = (((ci & 7) ^ (row & 7)) << 3);  // inverse-swizzled src octet
      gld_lds16(A + (size_t)(m0 + row) * 512 + k0 + c8, &As[0][0] + ci * 8);
      gld_lds16(B + (size_t)(n0 + row) * 512 + k0 + c8, &Bs[0][0] + ci * 8);
    }
    __syncthreads();
    #pragma unroll
    for (int kk = 0; kk < 64; kk += 32) {
      bf16x8 af[4], bf[4];
      #pragma unroll
      for (int fr = 0; fr < 4; ++fr)
        af[fr] = *(const bf16x8*)swz(&As[0][0], wr * 64 + fr * 16 + lr, kk + lq * 8, 64);
      #pragma unroll
      for (int fc = 0; fc < 4; ++fc)
        bf[fc] = *(const bf16x8*)swz(&Bs[0][0], wc * 64 + fc * 16 + lr, kk + lq * 8, 64);
      #pragma unroll
      for (int fr = 0; fr < 4; ++fr)
        #pragma unroll
        for (int fc = 0; fc < 4; ++fc)
          acc[fr][fc] = MFMA16(af[fr], bf[fc], acc[fr][fc], 0, 0, 0);
    }
    __syncthreads();
  }
  // epilogue: exp2(s*scale), rowsum partial over this wave's 64 cols, stores
  const float SCL2 = 0.06376774487989831f;   // log2(e)/sqrt(512)
  #pragma unroll
  for (int fr = 0; fr < 4; ++fr) {
    #pragma unroll
    for (int reg = 0; reg < 4; ++reg) {
      float rsum = 0.0f;
      const int row = m0 + wr * 64 + fr * 16 + lq * 4 + reg;
      u16* prow = Pexp + (size_t)row * 4096 + n0 + wc * 64 + lr;
      #pragma unroll
      for (int fc = 0; fc < 4; ++fc) {
        float p = exp2f(acc[fr][fc][reg] * SCL2);
        rsum += p;
        prow[fc * 16] = f2bf(p);
      }
      rsum += __shfl_xor(rsum, 1);
      rsum += __shfl_xor(rsum, 2);
      rsum += __shfl_xor(rsum, 4);
      rsum += __shfl_xor(rsum, 8);
      if (lr == 0)
        rsp[(size_t)(blockIdx.y * 2 + wc) * NTOK + gi0 + row] = rsum;
    }
  }
}

// ---------------- rowsum reduce: rinv[i] = 1/sum_j rsp[j][i] ----------------
__global__ __launch_bounds__(512) void rs_reduce_kernel(const float* __restrict__ rsp,
                                                        float* __restrict__ rinv, int gi0) {
  const int i = gi0 + blockIdx.x * 512 + threadIdx.x;
  float s = 0.0f;
  #pragma unroll 8
  for (int jg = 0; jg < 64; ++jg) s += rsp[(size_t)jg * NTOK + i];
  rinv[i] = 1.0f / s;
}

// ---------------- PV GEMM split-K: Op[sp] = Pexp @ V^T over K-half sp -------
// Per batch. A=Pexp [4096][4096]; B=vm[b] channel-major rows [512][tok].
// Tile 64x64, BK=64, K=2048 per split. grid (64, 8, 2) = 1024 blocks.
// LDS tiles XOR-swizzled (inverse-swizzled global src + swizzled ds_read).
__global__ __launch_bounds__(256, 4) void pvgemm_splitk(
    const u16* __restrict__ A, const u16* __restrict__ B,
    u16* __restrict__ Op0, u16* __restrict__ Op1)
{
  const int t = threadIdx.x;
  const int m0 = blockIdx.x * 64, n0 = blockIdx.y * 64;
  const int wv = t >> 6, l = t & 63, lr = l & 15, lq = l >> 4;
  const int wr = wv >> 1, wc = wv & 1;       // 2x2 waves of 32x32
  __shared__ u16 As[64][64];
  __shared__ u16 Bs[64][64];
  f32x4 acc[2][2] = {};
  const int kbeg = blockIdx.z * 2048;
  for (int k0 = kbeg; k0 < kbeg + 2048; k0 += 64) {
    #pragma unroll
    for (int it = 0; it < 2; ++it) {
      const int ci = it * 256 + t;           // 512 chunks of 16B per buffer
      const int row = ci >> 3;
      const int c8 = (((ci & 7) ^ (row & 7)) << 3);  // inverse-swizzled src octet
      gld_lds16(A + (size_t)(m0 + row) * 4096 + k0 + c8, &As[0][0] + ci * 8);
      gld_lds16(B + (size_t)(n0 + row) * NTOK + k0 + c8, &Bs[0][0] + ci * 8);
    }
    __syncthreads();
    #pragma unroll
    for (int kk = 0; kk < 64; kk += 32) {
      bf16x8 af[2], bf[2];
      #pragma unroll
      for (int fr = 0; fr < 2; ++fr)
        af[fr] = *(const bf16x8*)swz(&As[0][0], wr * 32 + fr * 16 + lr, kk + lq * 8, 64);
      #pragma unroll
      for (int fc = 0; fc < 2; ++fc)
        bf[fc] = *(const bf16x8*)swz(&Bs[0][0], wc * 32 + fc * 16 + lr, kk + lq * 8, 64);
      #pragma unroll
      for (int fr = 0; fr < 2; ++fr)
        #pragma unroll
        for (int fc = 0; fc < 2; ++fc)
          acc[fr][fc] = MFMA16(af[fr], bf[fc], acc[fr][fc], 0, 0, 0);
    }
    __syncthreads();
  }
  u16* Op = blockIdx.z ? Op1 : Op0;
  #pragma unroll
  for (int fr = 0; fr < 2; ++fr) {
    #pragma unroll
    for (int reg = 0; reg < 4; ++reg) {
      const int m = m0 + wr * 32 + fr * 16 + lq * 4 + reg;
      u16* orow = Op + (size_t)m * 512 + n0 + wc * 32 + lr;
      #pragma unroll
      for (int fc = 0; fc < 2; ++fc)
        orow[fc * 16] = f2bf(acc[fr][fc][reg]);
    }
  }
}

// ---------------- combine split-K partials, normalize by rinv, -> ao --------
__global__ __launch_bounds__(256) void combine_norm(const u16* __restrict__ Op0,
                                                    const u16* __restrict__ Op1,
                                                    const float* __restrict__ rinv,
                                                    u16* __restrict__ ao) {
  const size_t idx8 = ((size_t)blockIdx.x * 256 + threadIdx.x) * 8;  // < 4096*512
  const float ri = rinv[idx8 >> 9];
  ushort4 a0 = *(const ushort4*)(Op0 + idx8);
  ushort4 a1 = *(const ushort4*)(Op0 + idx8 + 4);
  ushort4 b0 = *(const ushort4*)(Op1 + idx8);
  ushort4 b1 = *(const ushort4*)(Op1 + idx8 + 4);
  ushort4 o0, o1;
  o0.x = f2bf((bf2f(a0.x) + bf2f(b0.x)) * ri);
  o0.y = f2bf((bf2f(a0.y) + bf2f(b0.y)) * ri);
  o0.z = f2bf((bf2f(a0.z) + bf2f(b0.z)) * ri);
  o0.w = f2bf((bf2f(a0.w) + bf2f(b0.w)) * ri);
  o1.x = f2bf((bf2f(a1.x) + bf2f(b1.x)) * ri);
  o1.y = f2bf((bf2f(a1.y) + bf2f(b1.y)) * ri);
  o1.z = f2bf((bf2f(a1.z) + bf2f(b1.z)) * ri);
  o1.w = f2bf((bf2f(a1.w) + bf2f(b1.w)) * ri);
  *(ushort4*)(ao + idx8)     = o0;
  *(ushort4*)(ao + idx8 + 4) = o1;
}

extern "C" void kernel_launch(void* const* d_in, const int* in_sizes, int n_in,
                              void* d_out, int out_size, void* d_ws, size_t ws_size,
                              hipStream_t stream) {
  const float* x   = (const float*)d_in[0];
  const float* gnw = (const float*)d_in[1];
  const float* gnb = (const float*)d_in[2];
  const float* qw  = (const float*)d_in[3];
  const float* qb  = (const float*)d_in[4];
  const float* kw  = (const float*)d_in[5];
  const float* kb  = (const float*)d_in[6];
  const float* vw  = (const float*)d_in[7];
  const float* vb  = (const float*)d_in[8];
  const float* pw  = (const float*)d_in[9];
  const float* pb  = (const float*)d_in[10];

  // workspace layout (71,336,448 bytes peak; 77.66MB proven available)
  char* ws = (char*)d_ws;
  u16*   wqb   = (u16*)(ws + 0);             // 4x 512x512 bf16 (2MB)
  u16*   wkb   = wqb + 262144;
  u16*   wvb   = wkb + 262144;
  u16*   wpb   = wvb + 262144;
  float* gstat = (float*)(ws + 2097152);     // 64 x (mean, rstd)
  float* rinv  = (float*)(ws + 2097664);     // [8192] f32
  float* rsp   = (float*)(ws + 2130432);     // [64][8192] f32 (2MB)
  u16*   hT    = (u16*)(ws + 4227584);       // [8192][512] bf16 (8MB), dead after v-GEMM
  u16*   ao    = hT;                         // reuses hT region: [2][4096][512] bf16
  u16*   qm    = (u16*)(ws + 12616192);      // [8192][512] bf16
  u16*   km    = (u16*)(ws + 21004800);      // [8192][512] bf16
  u16*   vm    = (u16*)(ws + 29393408);      // [512][8192] bf16
  u16*   Pexp  = (u16*)(ws + 37782016);      // [4096][4096] bf16 (33.5MB, per-batch reuse)
  // split-K partials: qm[b0]/km[b0] slices are dead once any pvgemm runs
  u16*   Op0   = qm;                         // [4096][512] bf16 (4MB)
  u16*   Op1   = km;                         // [4096][512] bf16 (4MB)

  wcast_kernel<<<1024, 256, 0, stream>>>(qw, kw, vw, pw, wqb);
  gn_stats_kernel<<<64, 256, 0, stream>>>(x, gstat);
  gn_apply_kernel<<<dim3(64, 8, 2), 256, 0, stream>>>(x, gnw, gnb, gstat, hT);
  // q, k: token-major, bias per-n
  gemm_abt<1, 0><<<dim3(128, 8), 256, 0, stream>>>(hT, 512, wqb, 512, 0, qb, nullptr, qm, 512, 0, 512);
  gemm_abt<1, 0><<<dim3(128, 8), 256, 0, stream>>>(hT, 512, wkb, 512, 0, kb, nullptr, km, 512, 0, 512);
  // v: channel-major, bias per-m
  gemm_abt<0, 0><<<dim3(8, 128), 256, 0, stream>>>(wvb, 512, hT, 512, 0, vb, nullptr, vm, 8192, 0, 512);

  for (int b = 0; b < 2; ++b) {
    const u16* qmb = qm + (size_t)b * HW_ * C_;
    const u16* kmb = km + (size_t)b * HW_ * C_;
    sgemm_exp_kernel<<<dim3(32, 32), 256, 0, stream>>>(qmb, kmb, Pexp, rsp, b * HW_);
    rs_reduce_kernel<<<8, 512, 0, stream>>>(rsp, rinv, b * HW_);
    pvgemm_splitk<<<dim3(64, 8, 2), 256, 0, stream>>>(Pexp, vm + (size_t)b * HW_, Op0, Op1);
    combine_norm<<<1024, 256, 0, stream>>>(Op0, Op1, rinv + b * HW_, ao + (size_t)b * HW_ * C_);
  }
  // proj + bias + residual, fp32 out, per-batch via blockIdx.z
  gemm_abt<0, 1><<<dim3(8, 64, 2), 256, 0, stream>>>(wpb, 512, ao, 512, 2097152L, pb, x, d_out, 4096, 2097152L, 512);
}

// Round 6
// 196.604 us; speedup vs baseline: 2.0089x; 1.0728x over previous
//
#include <hip/hip_runtime.h>

#define C_   512
#define HW_  4096
#define NTOK 8192
#define PZ_  16777216L   // Pexp batch stride (elems) in big mode

typedef __attribute__((ext_vector_type(8))) short bf16x8;
typedef __attribute__((ext_vector_type(4))) float f32x4;
typedef unsigned short u16;

#define MFMA16 __builtin_amdgcn_mfma_f32_16x16x32_bf16

__device__ __forceinline__ u16 f2bf(float f) {
  unsigned int u = __float_as_uint(f);
  u += 0x7fffu + ((u >> 16) & 1u);
  return (u16)(u >> 16);
}

__device__ __forceinline__ float bf2f(u16 v) {
  return __uint_as_float((unsigned)v << 16);
}

__device__ __forceinline__ void gld_lds16(const u16* g, u16* l) {
  __builtin_amdgcn_global_load_lds(
      (const __attribute__((address_space(1))) void*)g,
      (__attribute__((address_space(3))) void*)l, 16, 0, 0);
}

// swizzled LDS chunk address: logical (row, u16-col) -> physical u16 offset.
// Layout: within each row (8 chunks of 16B), chunk o stored at o ^ (row&7).
// Paired with inverse-swizzled global source in the staging loop.
__device__ __forceinline__ const u16* swz(const u16* base, int row, int col, int ldu16) {
  return base + (size_t)row * ldu16 + ((((col >> 3) ^ (row & 7)) << 3) | (col & 7));
}

// ---------------- weight fp32 -> bf16 cast (4 matrices of 512x512) ----------
__global__ void wcast_kernel(const float* __restrict__ a, const float* __restrict__ b,
                             const float* __restrict__ c, const float* __restrict__ d,
                             u16* __restrict__ out) {
  int gid = blockIdx.x * 256 + threadIdx.x;   // 262144 threads, 4 floats each
  int which = gid >> 16;
  const float* src = which == 0 ? a : which == 1 ? b : which == 2 ? c : d;
  int loc = (gid & 65535) * 4;
  float4 v = *(const float4*)(src + loc);
  ushort4 o;
  o.x = f2bf(v.x); o.y = f2bf(v.y); o.z = f2bf(v.z); o.w = f2bf(v.w);
  *(ushort4*)(out + ((size_t)which << 18) + loc) = o;
}

// ---------------- GroupNorm stats: one block per (batch, group) -------------
__global__ __launch_bounds__(256) void gn_stats_kernel(const float* __restrict__ x,
                                                       float* __restrict__ gstat) {
  const int blk = blockIdx.x;  // b*32+g, slice is contiguous 65536 floats
  const float4* p = (const float4*)(x + (size_t)blk * 65536);
  float s = 0.0f, ss = 0.0f;
  for (int i = threadIdx.x; i < 16384; i += 256) {
    float4 v = p[i];
    s  += v.x + v.y + v.z + v.w;
    ss += v.x * v.x + v.y * v.y + v.z * v.z + v.w * v.w;
  }
  #pragma unroll
  for (int m = 1; m < 64; m <<= 1) { s += __shfl_xor(s, m); ss += __shfl_xor(ss, m); }
  __shared__ float rs[4], rss[4];
  const int wv = threadIdx.x >> 6;
  if ((threadIdx.x & 63) == 0) { rs[wv] = s; rss[wv] = ss; }
  __syncthreads();
  if (threadIdx.x == 0) {
    float S  = rs[0] + rs[1] + rs[2] + rs[3];
    float SS = rss[0] + rss[1] + rss[2] + rss[3];
    float mean = S * (1.0f / 65536.0f);
    float var  = fmaxf(SS * (1.0f / 65536.0f) - mean * mean, 0.0f);
    gstat[2 * blk]     = mean;
    gstat[2 * blk + 1] = rsqrtf(var + 1e-6f);
  }
}

// ---------------- GN apply + transpose to token-major bf16 hT[8192][512] ----
__global__ __launch_bounds__(256) void gn_apply_kernel(const float* __restrict__ x,
                                                       const float* __restrict__ gnw,
                                                       const float* __restrict__ gnb,
                                                       const float* __restrict__ gstat,
                                                       u16* __restrict__ hT) {
  const int b = blockIdx.z, c0 = blockIdx.y * 64, hw0 = blockIdx.x * 64;
  const int t = threadIdx.x;
  __shared__ float tile[64][65];
  {
    const int tx = t & 63, ty = t >> 6;  // ty 0..3
    #pragma unroll
    for (int i = 0; i < 16; ++i) {
      int cl = ty * 16 + i;
      int c = c0 + cl;
      int g = b * 32 + (c >> 4);
      float mean = gstat[2 * g], rstd = gstat[2 * g + 1];
      float val = x[((size_t)(b * C_ + c)) * HW_ + hw0 + tx];
      tile[cl][tx] = (val - mean) * rstd * gnw[c] + gnb[c];
    }
  }
  __syncthreads();
  {
    const int cx = (t & 31) * 2, ty = t >> 5;  // ty 0..7
    #pragma unroll
    for (int i = 0; i < 8; ++i) {
      int hwl = ty * 8 + i;
      unsigned pk = (unsigned)f2bf(tile[cx][hwl]) | ((unsigned)f2bf(tile[cx + 1][hwl]) << 16);
      *(unsigned*)&hT[((size_t)(b * HW_ + hw0 + hwl)) * C_ + c0 + cx] = pk;
    }
  }
}

// ---------------- generic bf16 A(MxK) @ B(NxK)^T GEMM, 64x64 tile -----------
// BIAS_N: bias indexed by n (else by m). RESID: fp32 out + residual add.
template<int BIAS_N, int RESID>
__global__ __launch_bounds__(256, 4) void gemm_abt(
    const u16* __restrict__ A, int lda,
    const u16* __restrict__ B, int ldb, long bz,
    const float* __restrict__ bias,
    const float* __restrict__ resid,
    void* __restrict__ Dp, int ldd, long dz, int K)
{
  B += (size_t)blockIdx.z * (size_t)bz;
  const int t = threadIdx.x;
  const int m0 = blockIdx.x * 64, n0 = blockIdx.y * 64;
  const int wv = t >> 6, l = t & 63, lr = l & 15, lq = l >> 4;
  const int ro = (wv >> 1) * 32, co = (wv & 1) * 32;
  __shared__ u16 As[64][72];
  __shared__ u16 Bs[64][72];
  f32x4 acc[2][2] = {};
  const int ldr_ = t >> 2;
  const int ldc_ = (t & 3) * 16;
  for (int k0 = 0; k0 < K; k0 += 64) {
    *(uint4*)&As[ldr_][ldc_]     = *(const uint4*)(A + (size_t)(m0 + ldr_) * lda + k0 + ldc_);
    *(uint4*)&As[ldr_][ldc_ + 8] = *(const uint4*)(A + (size_t)(m0 + ldr_) * lda + k0 + ldc_ + 8);
    *(uint4*)&Bs[ldr_][ldc_]     = *(const uint4*)(B + (size_t)(n0 + ldr_) * ldb + k0 + ldc_);
    *(uint4*)&Bs[ldr_][ldc_ + 8] = *(const uint4*)(B + (size_t)(n0 + ldr_) * ldb + k0 + ldc_ + 8);
    __syncthreads();
    #pragma unroll
    for (int kk = 0; kk < 64; kk += 32) {
      bf16x8 a0 = *(const bf16x8*)&As[ro + lr][kk + lq * 8];
      bf16x8 a1 = *(const bf16x8*)&As[ro + 16 + lr][kk + lq * 8];
      bf16x8 b0 = *(const bf16x8*)&Bs[co + lr][kk + lq * 8];
      bf16x8 b1 = *(const bf16x8*)&Bs[co + 16 + lr][kk + lq * 8];
      acc[0][0] = MFMA16(a0, b0, acc[0][0], 0, 0, 0);
      acc[0][1] = MFMA16(a0, b1, acc[0][1], 0, 0, 0);
      acc[1][0] = MFMA16(a1, b0, acc[1][0], 0, 0, 0);
      acc[1][1] = MFMA16(a1, b1, acc[1][1], 0, 0, 0);
    }
    __syncthreads();
  }
  #pragma unroll
  for (int rf = 0; rf < 2; ++rf) {
    #pragma unroll
    for (int cf = 0; cf < 2; ++cf) {
      const int n = n0 + co + cf * 16 + lr;
      const float bn = BIAS_N ? bias[n] : 0.0f;
      #pragma unroll
      for (int reg = 0; reg < 4; ++reg) {
        const int m = m0 + ro + rf * 16 + lq * 4 + reg;
        float val = acc[rf][cf][reg] + (BIAS_N ? bn : bias[m]);
        if (RESID) {
          float* D = (float*)Dp + (size_t)blockIdx.z * dz;
          const float* R = resid + (size_t)blockIdx.z * dz;
          size_t idx = (size_t)m * ldd + n;
          D[idx] = val + R[idx];
        } else {
          ((u16*)Dp)[(size_t)m * ldd + n] = f2bf(val);
        }
      }
    }
  }
}

// ---------------- S-GEMM + exp + rowsum partials (m97 structure) ------------
// z = batch (big mode) or 0 (fallback; host pre-offsets pointers).
// A=qm[z] [4096][512], B=km[z] [4096][512]. Tile 128x128, BK=64.
// LDS tiles XOR-swizzled (inverse-swizzled global src + swizzled ds_read).
__global__ __launch_bounds__(256, 2) void sgemm_exp_kernel(
    const u16* __restrict__ A, const u16* __restrict__ B,
    u16* __restrict__ Pexp, float* __restrict__ rsp, long pz, int gi0base)
{
  const int z = blockIdx.z;
  A    += (size_t)z * (HW_ * C_);
  B    += (size_t)z * (HW_ * C_);
  Pexp += (size_t)z * pz;
  const int gi0 = gi0base + z * HW_;
  const int t = threadIdx.x;
  const int m0 = blockIdx.x * 128, n0 = blockIdx.y * 128;
  const int wv = t >> 6, l = t & 63, lr = l & 15, lq = l >> 4;
  const int wr = wv >> 1, wc = wv & 1;       // 2x2 waves of 64x64
  __shared__ u16 As[128][64];
  __shared__ u16 Bs[128][64];
  f32x4 acc[4][4] = {};
  for (int k0 = 0; k0 < 512; k0 += 64) {
    #pragma unroll
    for (int it = 0; it < 4; ++it) {
      const int ci = it * 256 + t;           // 1024 chunks of 16B
      const int row = ci >> 3;
      const int c8 = (((ci & 7) ^ (row & 7)) << 3);  // inverse-swizzled src octet
      gld_lds16(A + (size_t)(m0 + row) * 512 + k0 + c8, &As[0][0] + ci * 8);
      gld_lds16(B + (size_t)(n0 + row) * 512 + k0 + c8, &Bs[0][0] + ci * 8);
    }
    __syncthreads();
    #pragma unroll
    for (int kk = 0; kk < 64; kk += 32) {
      bf16x8 af[4], bf[4];
      #pragma unroll
      for (int fr = 0; fr < 4; ++fr)
        af[fr] = *(const bf16x8*)swz(&As[0][0], wr * 64 + fr * 16 + lr, kk + lq * 8, 64);
      #pragma unroll
      for (int fc = 0; fc < 4; ++fc)
        bf[fc] = *(const bf16x8*)swz(&Bs[0][0], wc * 64 + fc * 16 + lr, kk + lq * 8, 64);
      #pragma unroll
      for (int fr = 0; fr < 4; ++fr)
        #pragma unroll
        for (int fc = 0; fc < 4; ++fc)
          acc[fr][fc] = MFMA16(af[fr], bf[fc], acc[fr][fc], 0, 0, 0);
    }
    __syncthreads();
  }
  // epilogue: exp2(s*scale), rowsum partial over this wave's 64 cols, stores
  const float SCL2 = 0.06376774487989831f;   // log2(e)/sqrt(512)
  #pragma unroll
  for (int fr = 0; fr < 4; ++fr) {
    #pragma unroll
    for (int reg = 0; reg < 4; ++reg) {
      float rsum = 0.0f;
      const int row = m0 + wr * 64 + fr * 16 + lq * 4 + reg;
      u16* prow = Pexp + (size_t)row * 4096 + n0 + wc * 64 + lr;
      #pragma unroll
      for (int fc = 0; fc < 4; ++fc) {
        float p = exp2f(acc[fr][fc][reg] * SCL2);
        rsum += p;
        prow[fc * 16] = f2bf(p);
      }
      rsum += __shfl_xor(rsum, 1);
      rsum += __shfl_xor(rsum, 2);
      rsum += __shfl_xor(rsum, 4);
      rsum += __shfl_xor(rsum, 8);
      if (lr == 0)
        rsp[(size_t)(blockIdx.y * 2 + wc) * NTOK + gi0 + row] = rsum;
    }
  }
}

// ---------------- rowsum reduce: rinv[i] = 1/sum_j rsp[j][i] ----------------
__global__ __launch_bounds__(512) void rs_reduce_kernel(const float* __restrict__ rsp,
                                                        float* __restrict__ rinv, int gi0) {
  const int i = gi0 + blockIdx.x * 512 + threadIdx.x;
  float s = 0.0f;
  #pragma unroll 8
  for (int jg = 0; jg < 64; ++jg) s += rsp[(size_t)jg * NTOK + i];
  rinv[i] = 1.0f / s;
}

// ---------------- PV GEMM split-K: Op[sp] = Pexp @ V^T over K-half sp -------
// z encodes (split, batch): sp = z&1, b = z>>1 (fallback: z-extent 2, b=0,
// host pre-offsets pointers). A=Pexp [4096][4096]; B=vm channel-major rows.
// Tile 64x64, BK=64, K=2048 per split.
// LDS tiles XOR-swizzled (inverse-swizzled global src + swizzled ds_read).
__global__ __launch_bounds__(256, 8) void pvgemm_splitk(
    const u16* __restrict__ A, const u16* __restrict__ B,
    u16* __restrict__ Op0, u16* __restrict__ Op1)
{
  const int z = blockIdx.z;
  const int bb = z >> 1;
  A += (size_t)bb * PZ_;
  B += (size_t)bb * HW_;
  u16* Op = (z & 1) ? Op1 : Op0;
  Op += (size_t)bb * (HW_ * C_);
  const int t = threadIdx.x;
  const int m0 = blockIdx.x * 64, n0 = blockIdx.y * 64;
  const int wv = t >> 6, l = t & 63, lr = l & 15, lq = l >> 4;
  const int wr = wv >> 1, wc = wv & 1;       // 2x2 waves of 32x32
  __shared__ u16 As[64][64];
  __shared__ u16 Bs[64][64];
  f32x4 acc[2][2] = {};
  const int kbeg = (z & 1) * 2048;
  for (int k0 = kbeg; k0 < kbeg + 2048; k0 += 64) {
    #pragma unroll
    for (int it = 0; it < 2; ++it) {
      const int ci = it * 256 + t;           // 512 chunks of 16B per buffer
      const int row = ci >> 3;
      const int c8 = (((ci & 7) ^ (row & 7)) << 3);  // inverse-swizzled src octet
      gld_lds16(A + (size_t)(m0 + row) * 4096 + k0 + c8, &As[0][0] + ci * 8);
      gld_lds16(B + (size_t)(n0 + row) * NTOK + k0 + c8, &Bs[0][0] + ci * 8);
    }
    __syncthreads();
    #pragma unroll
    for (int kk = 0; kk < 64; kk += 32) {
      bf16x8 af[2], bf[2];
      #pragma unroll
      for (int fr = 0; fr < 2; ++fr)
        af[fr] = *(const bf16x8*)swz(&As[0][0], wr * 32 + fr * 16 + lr, kk + lq * 8, 64);
      #pragma unroll
      for (int fc = 0; fc < 2; ++fc)
        bf[fc] = *(const bf16x8*)swz(&Bs[0][0], wc * 32 + fc * 16 + lr, kk + lq * 8, 64);
      #pragma unroll
      for (int fr = 0; fr < 2; ++fr)
        #pragma unroll
        for (int fc = 0; fc < 2; ++fc)
          acc[fr][fc] = MFMA16(af[fr], bf[fc], acc[fr][fc], 0, 0, 0);
    }
    __syncthreads();
  }
  #pragma unroll
  for (int fr = 0; fr < 2; ++fr) {
    #pragma unroll
    for (int reg = 0; reg < 4; ++reg) {
      const int m = m0 + wr * 32 + fr * 16 + lq * 4 + reg;
      u16* orow = Op + (size_t)m * 512 + n0 + wc * 32 + lr;
      #pragma unroll
      for (int fc = 0; fc < 2; ++fc)
        orow[fc * 16] = f2bf(acc[fr][fc][reg]);
    }
  }
}

// ---------------- combine split-K partials, normalize by rinv, -> ao --------
__global__ __launch_bounds__(256) void combine_norm(const u16* __restrict__ Op0,
                                                    const u16* __restrict__ Op1,
                                                    const float* __restrict__ rinv,
                                                    u16* __restrict__ ao) {
  const size_t idx8 = ((size_t)blockIdx.x * 256 + threadIdx.x) * 8;
  const float ri = rinv[idx8 >> 9];
  ushort4 a0 = *(const ushort4*)(Op0 + idx8);
  ushort4 a1 = *(const ushort4*)(Op0 + idx8 + 4);
  ushort4 b0 = *(const ushort4*)(Op1 + idx8);
  ushort4 b1 = *(const ushort4*)(Op1 + idx8 + 4);
  ushort4 o0, o1;
  o0.x = f2bf((bf2f(a0.x) + bf2f(b0.x)) * ri);
  o0.y = f2bf((bf2f(a0.y) + bf2f(b0.y)) * ri);
  o0.z = f2bf((bf2f(a0.z) + bf2f(b0.z)) * ri);
  o0.w = f2bf((bf2f(a0.w) + bf2f(b0.w)) * ri);
  o1.x = f2bf((bf2f(a1.x) + bf2f(b1.x)) * ri);
  o1.y = f2bf((bf2f(a1.y) + bf2f(b1.y)) * ri);
  o1.z = f2bf((bf2f(a1.z) + bf2f(b1.z)) * ri);
  o1.w = f2bf((bf2f(a1.w) + bf2f(b1.w)) * ri);
  *(ushort4*)(ao + idx8)     = o0;
  *(ushort4*)(ao + idx8 + 4) = o1;
}

extern "C" void kernel_launch(void* const* d_in, const int* in_sizes, int n_in,
                              void* d_out, int out_size, void* d_ws, size_t ws_size,
                              hipStream_t stream) {
  const float* x   = (const float*)d_in[0];
  const float* gnw = (const float*)d_in[1];
  const float* gnb = (const float*)d_in[2];
  const float* qw  = (const float*)d_in[3];
  const float* qb  = (const float*)d_in[4];
  const float* kw  = (const float*)d_in[5];
  const float* kb  = (const float*)d_in[6];
  const float* vw  = (const float*)d_in[7];
  const float* vb  = (const float*)d_in[8];
  const float* pw  = (const float*)d_in[9];
  const float* pb  = (const float*)d_in[10];

  // common prefix layout (both modes)
  char* ws = (char*)d_ws;
  u16*   wqb   = (u16*)(ws + 0);             // 4x 512x512 bf16 (2MB)
  u16*   wkb   = wqb + 262144;
  u16*   wvb   = wkb + 262144;
  u16*   wpb   = wvb + 262144;
  float* gstat = (float*)(ws + 2097152);     // 64 x (mean, rstd)
  float* rinv  = (float*)(ws + 2097664);     // [8192] f32
  float* rsp   = (float*)(ws + 2130432);     // [64][8192] f32 (2MB)
  u16*   hT    = (u16*)(ws + 4227584);       // [8192][512] bf16 (8MB), dead after v-GEMM
  u16*   ao    = hT;                         // reuses hT region: [2][4096][512] bf16
  u16*   qm    = (u16*)(ws + 12616192);      // [8192][512] bf16
  u16*   km    = (u16*)(ws + 21004800);      // [8192][512] bf16
  u16*   vm    = (u16*)(ws + 29393408);      // [512][8192] bf16

  // big mode (ws >= ~122MB): both-batch Pexp + separate Op partials
  const bool big = ws_size >= 121668096ULL;
  u16* Op0B  = (u16*)(ws + 37782016);        // [2][4096][512] bf16 (8MB)
  u16* Op1B  = (u16*)(ws + 46170624);        // [2][4096][512] bf16 (8MB)
  u16* PexpB = (u16*)(ws + 54559232);        // [2][4096][4096] bf16 (67MB)
  // fallback (ws >= 77.66MB proven): single-batch Pexp, Op aliases qm/km
  u16* PexpS = (u16*)(ws + 37782016);        // [4096][4096] bf16 (33.5MB)

  wcast_kernel<<<1024, 256, 0, stream>>>(qw, kw, vw, pw, wqb);
  gn_stats_kernel<<<64, 256, 0, stream>>>(x, gstat);
  gn_apply_kernel<<<dim3(64, 8, 2), 256, 0, stream>>>(x, gnw, gnb, gstat, hT);
  // q, k: token-major, bias per-n
  gemm_abt<1, 0><<<dim3(128, 8), 256, 0, stream>>>(hT, 512, wqb, 512, 0, qb, nullptr, qm, 512, 0, 512);
  gemm_abt<1, 0><<<dim3(128, 8), 256, 0, stream>>>(hT, 512, wkb, 512, 0, kb, nullptr, km, 512, 0, 512);
  // v: channel-major, bias per-m
  gemm_abt<0, 0><<<dim3(8, 128), 256, 0, stream>>>(wvb, 512, hT, 512, 0, vb, nullptr, vm, 8192, 0, 512);

  if (big) {
    sgemm_exp_kernel<<<dim3(32, 32, 2), 256, 0, stream>>>(qm, km, PexpB, rsp, PZ_, 0);
    rs_reduce_kernel<<<16, 512, 0, stream>>>(rsp, rinv, 0);
    pvgemm_splitk<<<dim3(64, 8, 4), 256, 0, stream>>>(PexpB, vm, Op0B, Op1B);
    combine_norm<<<2048, 256, 0, stream>>>(Op0B, Op1B, rinv, ao);
  } else {
    u16* Op0 = qm;   // qm/km slices dead once pvgemm runs
    u16* Op1 = km;
    for (int b = 0; b < 2; ++b) {
      const u16* qmb = qm + (size_t)b * HW_ * C_;
      const u16* kmb = km + (size_t)b * HW_ * C_;
      sgemm_exp_kernel<<<dim3(32, 32, 1), 256, 0, stream>>>(qmb, kmb, PexpS, rsp, 0L, b * HW_);
      rs_reduce_kernel<<<8, 512, 0, stream>>>(rsp, rinv, b * HW_);
      pvgemm_splitk<<<dim3(64, 8, 2), 256, 0, stream>>>(PexpS, vm + (size_t)b * HW_, Op0, Op1);
      combine_norm<<<1024, 256, 0, stream>>>(Op0, Op1, rinv + b * HW_, ao + (size_t)b * HW_ * C_);
    }
  }
  // proj + bias + residual, fp32 out, per-batch via blockIdx.z
  gemm_abt<0, 1><<<dim3(8, 64, 2), 256, 0, stream>>>(wpb, 512, ao, 512, 2097152L, pb, x, d_out, 4096, 2097152L, 512);
}